// Round 7
// baseline (743.272 us; speedup 1.0000x reference)
//
#include <hip/hip_runtime.h>
#include <cstdint>
#include <cstddef>

constexpr int kN   = 50000;          // nodes
constexpr int kE   = 800000;         // edges (without self loops)
constexpr int kEt  = kE + kN;        // edges + self loops
constexpr float kSlope = 0.2f;       // leaky relu slope

// ---------------- static device workspace (d_ws unused) ---------------------
__device__ __align__(16) float g_aggx[(size_t)kN * 512]; // normalized per-head agg of x
__device__ __align__(16) float g_h1b [(size_t)kN * 512]; // layer-1 output
__device__ __align__(16) float g_h2  [(size_t)kN * 128]; // layer-2 pre-agg features
__device__ __align__(16) float g_h2p [4][(size_t)kN * 128]; // split-K partials
__device__ __align__(16) float g_es1[kN * 4];
__device__ __align__(16) float g_ed1[kN * 4];
__device__ float g_es2[kN];
__device__ float g_ed2[kN];
__device__ __align__(16) float g_p1s[4 * 128];  // folded W1_h @ a1_src_h
__device__ __align__(16) float g_p1d[4 * 128];
// CSR by destination:
__device__ int g_deg[kN];
__device__ int g_ptr[kN + 1];
__device__ int g_cur[kN];
__device__ int g_srcs[kEt];

__device__ __forceinline__ float lrelu(float x) { return x > 0.f ? x : kSlope * x; }

// ------------------------- CSR build ----------------------------------------
__global__ __launch_bounds__(256) void k_zero_deg() {
  int i = blockIdx.x * 256 + threadIdx.x;
  if (i < kN) g_deg[i] = 0;
}

__global__ __launch_bounds__(256) void k_hist(const int* __restrict__ ei) {
  int e = blockIdx.x * 256 + threadIdx.x;
  if (e >= kEt) return;
  int d = (e < kE) ? ei[kE + e] : e - kE;
  atomicAdd(&g_deg[d], 1);
}

__global__ __launch_bounds__(256) void k_scan() {
  __shared__ int s_sum[256];
  const int t = threadIdx.x;
  const int chunk = (kN + 255) / 256;
  const int lo = t * chunk, hi = min(lo + chunk, kN);
  int sum = 0;
  for (int i = lo; i < hi; ++i) sum += g_deg[i];
  s_sum[t] = sum;
  __syncthreads();
  for (int off = 1; off < 256; off <<= 1) {
    int xv = s_sum[t];
    int yv = (t >= off) ? s_sum[t - off] : 0;
    __syncthreads();
    s_sum[t] = xv + yv;
    __syncthreads();
  }
  int run = s_sum[t] - sum;
  for (int i = lo; i < hi; ++i) {
    g_ptr[i] = run;
    g_cur[i] = run;
    run += g_deg[i];
  }
  if (t == 255) g_ptr[kN] = run;
}

__global__ __launch_bounds__(256) void k_scatter(const int* __restrict__ ei) {
  int e = blockIdx.x * 256 + threadIdx.x;
  if (e >= kEt) return;
  int s, d;
  if (e < kE) { s = ei[e]; d = ei[kE + e]; } else { s = d = e - kE; }
  int slot = atomicAdd(&g_cur[d], 1);
  g_srcs[slot] = s;
}

// ---- fold attention vectors through W1 ----
__global__ __launch_bounds__(256) void k_prep1(const float* __restrict__ W1,
    const float* __restrict__ a1s, const float* __restrict__ a1d) {
  int gid = blockIdx.x * 256 + threadIdx.x;
  if (gid >= 1024) return;
  int which = gid >> 9, idx = gid & 511;
  int h = idx >> 7, k = idx & 127;
  const float* a = which ? a1d : a1s;
  const float* wrow = W1 + (size_t)k * 512 + h * 128;
  float s = 0.f;
#pragma unroll 8
  for (int c = 0; c < 128; ++c) s += wrow[c] * a[h * 128 + c];
  (which ? g_p1d : g_p1s)[idx] = s;
}

// ---- layer-1 scores directly from x ----
__global__ __launch_bounds__(256) void k_scores1x(const float* __restrict__ x) {
  const int lane = threadIdx.x & 63;
  const int n = (blockIdx.x * 256 + threadIdx.x) >> 6;
  if (n >= kN) return;
  float x0 = x[(size_t)n * 128 + lane];
  float x1 = x[(size_t)n * 128 + 64 + lane];
  float s[4], d[4];
#pragma unroll
  for (int h = 0; h < 4; ++h) {
    s[h] = x0 * g_p1s[h * 128 + lane] + x1 * g_p1s[h * 128 + 64 + lane];
    d[h] = x0 * g_p1d[h * 128 + lane] + x1 * g_p1d[h * 128 + 64 + lane];
  }
#pragma unroll
  for (int off = 32; off > 0; off >>= 1) {
#pragma unroll
    for (int h = 0; h < 4; ++h) {
      s[h] += __shfl_down(s[h], off);
      d[h] += __shfl_down(d[h], off);
    }
  }
  if (lane == 0) {
    *(float4*)(g_es1 + (size_t)n * 4) = make_float4(s[0], s[1], s[2], s[3]);
    *(float4*)(g_ed1 + (size_t)n * 4) = make_float4(d[0], d[1], d[2], d[3]);
  }
}

// ---- layer-1 aggregation of x rows (pre-projection), normalized ----
__global__ __launch_bounds__(256) void k_agg1x(const float* __restrict__ x) {
  const int lane = threadIdx.x & 63;
  const int n = (blockIdx.x * 256 + threadIdx.x) >> 6;
  if (n >= kN) return;
  const int beg = g_ptr[n], end = g_ptr[n + 1];
  const float4 ed = *(const float4*)(g_ed1 + (size_t)n * 4);
  const int coff = lane * 2;
  float z0 = 0.f, z1 = 0.f, z2 = 0.f, z3 = 0.f;
  float a00 = 0.f, a01 = 0.f, a10 = 0.f, a11 = 0.f;
  float a20 = 0.f, a21 = 0.f, a30 = 0.f, a31 = 0.f;
  for (int base = beg; base < end; base += 64) {
    const int cnt = min(64, end - base);
    int s = 0;
    float w0 = 0.f, w1 = 0.f, w2 = 0.f, w3 = 0.f;
    if (lane < cnt) {
      s = g_srcs[base + lane];
      float4 es = *(const float4*)(g_es1 + (size_t)s * 4);
      w0 = __expf(lrelu(es.x + ed.x));
      w1 = __expf(lrelu(es.y + ed.y));
      w2 = __expf(lrelu(es.z + ed.z));
      w3 = __expf(lrelu(es.w + ed.w));
      z0 += w0; z1 += w1; z2 += w2; z3 += w3;
    }
    for (int j = 0; j < cnt; ++j) {
      int   sj = __shfl(s, j);
      float b0 = __shfl(w0, j), b1 = __shfl(w1, j);
      float b2 = __shfl(w2, j), b3 = __shfl(w3, j);
      float2 f = *(const float2*)(x + (size_t)sj * 128 + coff);
      a00 += b0 * f.x; a01 += b0 * f.y;
      a10 += b1 * f.x; a11 += b1 * f.y;
      a20 += b2 * f.x; a21 += b2 * f.y;
      a30 += b3 * f.x; a31 += b3 * f.y;
    }
  }
#pragma unroll
  for (int off = 1; off < 64; off <<= 1) {
    z0 += __shfl_xor(z0, off); z1 += __shfl_xor(z1, off);
    z2 += __shfl_xor(z2, off); z3 += __shfl_xor(z3, off);
  }
  float i0 = 1.f / z0, i1 = 1.f / z1, i2 = 1.f / z2, i3 = 1.f / z3;
  float* op = g_aggx + (size_t)n * 512;
  *(float2*)(op + 0 * 128 + coff) = make_float2(a00 * i0, a01 * i0);
  *(float2*)(op + 1 * 128 + coff) = make_float2(a10 * i1, a11 * i1);
  *(float2*)(op + 2 * 128 + coff) = make_float2(a20 * i2, a21 * i2);
  *(float2*)(op + 3 * 128 + coff) = make_float2(a30 * i3, a31 * i3);
}

// ------- f32 GEMM: 128x128 tile, BK=16, 512 threads, 4x8/thread -------------
// Double-buffered LDS: one barrier per K-iter; global loads for iter i+1
// issued before computing iter i (latency hidden under 512 FMAs).
__device__ __forceinline__ void gemm128_db(const float* __restrict__ A, int lda,
    const float* __restrict__ B, int ldb, float* __restrict__ C, int ldc,
    int M, int K, const float* __restrict__ bias, bool relu) {
  __shared__ float As[2][16][132];
  __shared__ float Bs[2][16][132];
  const int t = threadIdx.x;
  const int row0 = blockIdx.y * 128;
  const int arow = t & 127, ak = (t >> 7) * 4;  // A stage: [arow][ak..ak+3]
  const int bk = t >> 5, bc = (t & 31) * 4;     // B stage: [bk][bc..bc+3]
  const int tx = t & 15, ty = t >> 4;           // ty 0..31
  const int niter = K / 16;
  const bool arow_ok = (row0 + arow < M);
  float acc[4][8] = {};

  // prologue: stage tile 0
  {
    float4 av = make_float4(0.f, 0.f, 0.f, 0.f);
    if (arow_ok) av = *(const float4*)&A[(size_t)(row0 + arow) * lda + ak];
    float4 bv = *(const float4*)&B[(size_t)bk * ldb + bc];
    As[0][ak + 0][arow] = av.x; As[0][ak + 1][arow] = av.y;
    As[0][ak + 2][arow] = av.z; As[0][ak + 3][arow] = av.w;
    *(float4*)&Bs[0][bk][bc] = bv;
  }
  __syncthreads();

  for (int it = 0; it < niter; ++it) {
    const int cur = it & 1, nxt = cur ^ 1;
    const bool have_next = (it + 1 < niter);
    float4 avn = make_float4(0.f, 0.f, 0.f, 0.f);
    float4 bvn = make_float4(0.f, 0.f, 0.f, 0.f);
    if (have_next) {
      const int k0 = (it + 1) * 16;
      if (arow_ok) avn = *(const float4*)&A[(size_t)(row0 + arow) * lda + k0 + ak];
      bvn = *(const float4*)&B[(size_t)(k0 + bk) * ldb + bc];
    }
#pragma unroll
    for (int kk = 0; kk < 16; ++kk) {
      float4 a0 = *(const float4*)&As[cur][kk][ty * 4];
      float4 b0 = *(const float4*)&Bs[cur][kk][tx * 4];
      float4 b1 = *(const float4*)&Bs[cur][kk][64 + tx * 4];
      float ar[4] = {a0.x, a0.y, a0.z, a0.w};
      float br[8] = {b0.x, b0.y, b0.z, b0.w, b1.x, b1.y, b1.z, b1.w};
#pragma unroll
      for (int i = 0; i < 4; ++i)
#pragma unroll
        for (int j = 0; j < 8; ++j) acc[i][j] += ar[i] * br[j];
    }
    if (have_next) {
      As[nxt][ak + 0][arow] = avn.x; As[nxt][ak + 1][arow] = avn.y;
      As[nxt][ak + 2][arow] = avn.z; As[nxt][ak + 3][arow] = avn.w;
      *(float4*)&Bs[nxt][bk][bc] = bvn;
    }
    __syncthreads();
  }

#pragma unroll
  for (int i = 0; i < 4; ++i) {
    int r = row0 + ty * 4 + i;
    if (r >= M) continue;
    float4 o0 = make_float4(acc[i][0], acc[i][1], acc[i][2], acc[i][3]);
    float4 o1 = make_float4(acc[i][4], acc[i][5], acc[i][6], acc[i][7]);
    if (bias) {
      float4 bb0 = *(const float4*)(bias + tx * 4);
      float4 bb1 = *(const float4*)(bias + 64 + tx * 4);
      o0.x += bb0.x; o0.y += bb0.y; o0.z += bb0.z; o0.w += bb0.w;
      o1.x += bb1.x; o1.y += bb1.y; o1.z += bb1.z; o1.w += bb1.w;
    }
    if (relu) {
      o0.x = fmaxf(o0.x, 0.f); o0.y = fmaxf(o0.y, 0.f);
      o0.z = fmaxf(o0.z, 0.f); o0.w = fmaxf(o0.w, 0.f);
      o1.x = fmaxf(o1.x, 0.f); o1.y = fmaxf(o1.y, 0.f);
      o1.z = fmaxf(o1.z, 0.f); o1.w = fmaxf(o1.w, 0.f);
    }
    *(float4*)&C[(size_t)r * ldc + tx * 4]      = o0;
    *(float4*)&C[(size_t)r * ldc + 64 + tx * 4] = o1;
  }
}

// expand: per head h, h1b[:, h*128:+128] = relu(aggx_h @ W1_h + b1_h); K=128
__global__ __launch_bounds__(512) void k_gemm_expand(const float* __restrict__ W1,
                                                     const float* __restrict__ b1) {
  const int h = blockIdx.z;
  gemm128_db(g_aggx + h * 128, 512, W1 + h * 128, 512, g_h1b + h * 128, 512,
             kN, 128, b1 + h * 128, true);
}
// layer-2 GEMM, split-K=4: slice z covers K rows [z*128, z*128+128)
__global__ __launch_bounds__(512) void k_gemm2x(const float* __restrict__ W2) {
  const int z = blockIdx.z;
  gemm128_db(g_h1b + z * 128, 512, W2 + (size_t)z * 128 * 128, 128,
             g_h2p[z], 128, kN, 128, nullptr, false);
}

// ---- fused partial-sum (4 slices) + layer-2 scores ----
__global__ __launch_bounds__(256) void k_scores2(const float* __restrict__ asrc,
                                                 const float* __restrict__ adst) {
  const int lane = threadIdx.x & 63;
  const int n = (blockIdx.x * 256 + threadIdx.x) >> 6;
  if (n >= kN) return;
  const size_t o = (size_t)n * 128;
  float v0 = g_h2p[0][o + lane]      + g_h2p[1][o + lane]
           + g_h2p[2][o + lane]      + g_h2p[3][o + lane];
  float v1 = g_h2p[0][o + 64 + lane] + g_h2p[1][o + 64 + lane]
           + g_h2p[2][o + 64 + lane] + g_h2p[3][o + 64 + lane];
  g_h2[o + lane] = v0;
  g_h2[o + 64 + lane] = v1;
  float s = v0 * asrc[lane] + v1 * asrc[64 + lane];
  float d = v0 * adst[lane] + v1 * adst[64 + lane];
#pragma unroll
  for (int off = 32; off > 0; off >>= 1) {
    s += __shfl_down(s, off);
    d += __shfl_down(d, off);
  }
  if (lane == 0) { g_es2[n] = s; g_ed2[n] = d; }
}

// ---- layer-2 aggregation (H=1) + fused FC epilogue ----
__global__ __launch_bounds__(256) void k_agg2x(const float* __restrict__ b2,
    const float* __restrict__ fcw, const float* __restrict__ fcb,
    float* __restrict__ out) {
  const int lane = threadIdx.x & 63;
  const int n = (blockIdx.x * 256 + threadIdx.x) >> 6;
  if (n >= kN) return;
  const int beg = g_ptr[n], end = g_ptr[n + 1];
  const float ed = g_ed2[n];
  const int coff = lane * 2;
  float zp = 0.f, a0 = 0.f, a1 = 0.f;
  for (int base = beg; base < end; base += 64) {
    const int cnt = min(64, end - base);
    int s = 0; float w = 0.f;
    if (lane < cnt) {
      s = g_srcs[base + lane];
      w = __expf(lrelu(g_es2[s] + ed));
      zp += w;
    }
    for (int j = 0; j < cnt; ++j) {
      int   sj = __shfl(s, j);
      float wj = __shfl(w, j);
      float2 f = *(const float2*)(g_h2 + (size_t)sj * 128 + coff);
      a0 += wj * f.x; a1 += wj * f.y;
    }
  }
#pragma unroll
  for (int off = 1; off < 64; off <<= 1) zp += __shfl_xor(zp, off);
  float invz = 1.f / zp;
  float v0 = a0 * invz + b2[coff];
  float v1 = a1 * invz + b2[coff + 1];
  float s = v0 * fcw[coff] + v1 * fcw[coff + 1];
#pragma unroll
  for (int off = 1; off < 64; off <<= 1) s += __shfl_xor(s, off);
  if (lane == 0) out[n] = s + fcb[0];
}

extern "C" void kernel_launch(void* const* d_in, const int* in_sizes, int n_in,
                              void* d_out, int out_size, void* d_ws, size_t ws_size,
                              hipStream_t stream) {
  const float* x   = (const float*)d_in[0];
  const int*   ei  = (const int*)d_in[1];
  const float* W1  = (const float*)d_in[2];
  const float* a1s = (const float*)d_in[3];
  const float* a1d = (const float*)d_in[4];
  const float* b1  = (const float*)d_in[5];
  const float* W2  = (const float*)d_in[6];
  const float* a2s = (const float*)d_in[7];
  const float* a2d = (const float*)d_in[8];
  const float* b2  = (const float*)d_in[9];
  const float* fcw = (const float*)d_in[10];
  const float* fcb = (const float*)d_in[11];
  float* out = (float*)d_out;
  (void)d_ws; (void)ws_size; (void)in_sizes; (void)n_in; (void)out_size;

  // ---- CSR build (dst-sorted) ----
  k_zero_deg<<<(kN + 255) / 256, 256, 0, stream>>>();
  k_hist<<<(kEt + 255) / 256, 256, 0, stream>>>(ei);
  k_scan<<<1, 256, 0, stream>>>();
  k_scatter<<<(kEt + 255) / 256, 256, 0, stream>>>(ei);

  // ---- layer 1 ----
  k_prep1<<<4, 256, 0, stream>>>(W1, a1s, a1d);
  k_scores1x<<<(kN * 64 + 255) / 256, 256, 0, stream>>>(x);
  k_agg1x<<<(kN * 64 + 255) / 256, 256, 0, stream>>>(x);
  dim3 ge(1, (kN + 127) / 128, 4);
  k_gemm_expand<<<ge, 512, 0, stream>>>(W1, b1);

  // ---- layer 2 ----
  dim3 g2(1, (kN + 127) / 128, 4);
  k_gemm2x<<<g2, 512, 0, stream>>>(W2);
  k_scores2<<<(kN * 64 + 255) / 256, 256, 0, stream>>>(a2s, a2d);
  k_agg2x<<<(kN * 64 + 255) / 256, 256, 0, stream>>>(b2, fcw, fcb, out);
}

// Round 8
// 690.878 us; speedup vs baseline: 1.0758x; 1.0758x over previous
//
#include <hip/hip_runtime.h>
#include <cstdint>
#include <cstddef>

constexpr int kN   = 50000;          // nodes
constexpr int kE   = 800000;         // edges (without self loops)
constexpr int kEt  = kE + kN;        // edges + self loops
constexpr float kSlope = 0.2f;       // leaky relu slope

typedef __attribute__((ext_vector_type(8))) short bf8_t;   // 8 bf16 = 4 VGPRs
typedef __attribute__((ext_vector_type(4))) float f4_t;

// ---------------- static device workspace (d_ws unused) ---------------------
__device__ __align__(16) unsigned short g_aggx_h[(size_t)kN * 512]; // agg of x, bf16 hi
__device__ __align__(16) unsigned short g_aggx_l[(size_t)kN * 512]; // bf16 lo residual
__device__ __align__(16) unsigned short g_h1b_h[(size_t)kN * 512];  // layer-1 out hi
__device__ __align__(16) unsigned short g_h1b_l[(size_t)kN * 512];  // layer-1 out lo
__device__ __align__(16) unsigned short g_w1t_h[4 * 128 * 128];     // W1^T per head, hi
__device__ __align__(16) unsigned short g_w1t_l[4 * 128 * 128];
__device__ __align__(16) unsigned short g_w2t_h[128 * 512];         // W2^T, hi
__device__ __align__(16) unsigned short g_w2t_l[128 * 512];
__device__ __align__(16) float g_h2  [(size_t)kN * 128];  // layer-2 pre-agg features
__device__ __align__(16) float g_h2p [2][(size_t)kN * 128]; // split-K partials
__device__ __align__(16) float g_es1[kN * 4];
__device__ __align__(16) float g_ed1[kN * 4];
__device__ float g_es2[kN];
__device__ float g_ed2[kN];
__device__ __align__(16) float g_p1s[4 * 128];  // folded W1_h @ a1_src_h
__device__ __align__(16) float g_p1d[4 * 128];
// CSR by destination:
__device__ int g_deg[kN];
__device__ int g_ptr[kN + 1];
__device__ int g_cur[kN];
__device__ int g_srcs[kEt];

__device__ __forceinline__ float lrelu(float x) { return x > 0.f ? x : kSlope * x; }

// round-to-nearest-even f32 -> bf16 (returns bits; hi_f = value as f32)
__device__ __forceinline__ unsigned short f2bf(float v, float& hi_f) {
  unsigned u = __float_as_uint(v);
  unsigned r = (u + 0x7FFFu + ((u >> 16) & 1u)) & 0xFFFF0000u;
  hi_f = __uint_as_float(r);
  return (unsigned short)(r >> 16);
}
__device__ __forceinline__ void split_bf(float v, unsigned short& h, unsigned short& l) {
  float hf, lf;
  h = f2bf(v, hf);
  l = f2bf(v - hf, lf);
}

// ------------------------- CSR build ----------------------------------------
__global__ __launch_bounds__(256) void k_zero_deg() {
  int i = blockIdx.x * 256 + threadIdx.x;
  if (i < kN) g_deg[i] = 0;
}

__global__ __launch_bounds__(256) void k_hist(const int* __restrict__ ei) {
  int e = blockIdx.x * 256 + threadIdx.x;
  if (e >= kEt) return;
  int d = (e < kE) ? ei[kE + e] : e - kE;
  atomicAdd(&g_deg[d], 1);
}

__global__ __launch_bounds__(256) void k_scan() {
  __shared__ int s_sum[256];
  const int t = threadIdx.x;
  const int chunk = (kN + 255) / 256;
  const int lo = t * chunk, hi = min(lo + chunk, kN);
  int sum = 0;
  for (int i = lo; i < hi; ++i) sum += g_deg[i];
  s_sum[t] = sum;
  __syncthreads();
  for (int off = 1; off < 256; off <<= 1) {
    int xv = s_sum[t];
    int yv = (t >= off) ? s_sum[t - off] : 0;
    __syncthreads();
    s_sum[t] = xv + yv;
    __syncthreads();
  }
  int run = s_sum[t] - sum;
  for (int i = lo; i < hi; ++i) {
    g_ptr[i] = run;
    g_cur[i] = run;
    run += g_deg[i];
  }
  if (t == 255) g_ptr[kN] = run;
}

__global__ __launch_bounds__(256) void k_scatter(const int* __restrict__ ei) {
  int e = blockIdx.x * 256 + threadIdx.x;
  if (e >= kEt) return;
  int s, d;
  if (e < kE) { s = ei[e]; d = ei[kE + e]; } else { s = d = e - kE; }
  int slot = atomicAdd(&g_cur[d], 1);
  g_srcs[slot] = s;
}

// ---- weight conversion: W1 -> per-head W1T hi/lo, W2 -> W2T hi/lo ----------
__global__ __launch_bounds__(256) void k_convw(const float* __restrict__ W1,
                                               const float* __restrict__ W2) {
  int gid = blockIdx.x * 256 + threadIdx.x;   // 0..131071
  if (gid < 65536) {
    int h = gid >> 14, rem = gid & 16383;
    int c = rem >> 7, j = rem & 127;          // read coalesced in j
    float v = W1[(size_t)c * 512 + h * 128 + j];
    unsigned short hh, ll;
    split_bf(v, hh, ll);
    size_t o = ((size_t)h * 128 + j) * 128 + c;
    g_w1t_h[o] = hh; g_w1t_l[o] = ll;
  } else {
    int g2 = gid - 65536;
    int k = g2 >> 7, j = g2 & 127;            // read coalesced in j
    float v = W2[(size_t)k * 128 + j];
    unsigned short hh, ll;
    split_bf(v, hh, ll);
    size_t o = (size_t)j * 512 + k;
    g_w2t_h[o] = hh; g_w2t_l[o] = ll;
  }
}

// ---- fold attention vectors through W1 ----
__global__ __launch_bounds__(256) void k_prep1(const float* __restrict__ W1,
    const float* __restrict__ a1s, const float* __restrict__ a1d) {
  int gid = blockIdx.x * 256 + threadIdx.x;
  if (gid >= 1024) return;
  int which = gid >> 9, idx = gid & 511;
  int h = idx >> 7, k = idx & 127;
  const float* a = which ? a1d : a1s;
  const float* wrow = W1 + (size_t)k * 512 + h * 128;
  float s = 0.f;
#pragma unroll 8
  for (int c = 0; c < 128; ++c) s += wrow[c] * a[h * 128 + c];
  (which ? g_p1d : g_p1s)[idx] = s;
}

// ---- layer-1 scores directly from x ----
__global__ __launch_bounds__(256) void k_scores1x(const float* __restrict__ x) {
  const int lane = threadIdx.x & 63;
  const int n = (blockIdx.x * 256 + threadIdx.x) >> 6;
  if (n >= kN) return;
  float x0 = x[(size_t)n * 128 + lane];
  float x1 = x[(size_t)n * 128 + 64 + lane];
  float s[4], d[4];
#pragma unroll
  for (int h = 0; h < 4; ++h) {
    s[h] = x0 * g_p1s[h * 128 + lane] + x1 * g_p1s[h * 128 + 64 + lane];
    d[h] = x0 * g_p1d[h * 128 + lane] + x1 * g_p1d[h * 128 + 64 + lane];
  }
#pragma unroll
  for (int off = 32; off > 0; off >>= 1) {
#pragma unroll
    for (int h = 0; h < 4; ++h) {
      s[h] += __shfl_down(s[h], off);
      d[h] += __shfl_down(d[h], off);
    }
  }
  if (lane == 0) {
    *(float4*)(g_es1 + (size_t)n * 4) = make_float4(s[0], s[1], s[2], s[3]);
    *(float4*)(g_ed1 + (size_t)n * 4) = make_float4(d[0], d[1], d[2], d[3]);
  }
}

// ---- layer-1 aggregation of x rows, normalized; emits bf16 hi/lo ----
__global__ __launch_bounds__(256) void k_agg1x(const float* __restrict__ x) {
  const int lane = threadIdx.x & 63;
  const int n = (blockIdx.x * 256 + threadIdx.x) >> 6;
  if (n >= kN) return;
  const int beg = g_ptr[n], end = g_ptr[n + 1];
  const float4 ed = *(const float4*)(g_ed1 + (size_t)n * 4);
  const int coff = lane * 2;
  float z0 = 0.f, z1 = 0.f, z2 = 0.f, z3 = 0.f;
  float a00 = 0.f, a01 = 0.f, a10 = 0.f, a11 = 0.f;
  float a20 = 0.f, a21 = 0.f, a30 = 0.f, a31 = 0.f;
  for (int base = beg; base < end; base += 64) {
    const int cnt = min(64, end - base);
    int s = 0;
    float w0 = 0.f, w1 = 0.f, w2 = 0.f, w3 = 0.f;
    if (lane < cnt) {
      s = g_srcs[base + lane];
      float4 es = *(const float4*)(g_es1 + (size_t)s * 4);
      w0 = __expf(lrelu(es.x + ed.x));
      w1 = __expf(lrelu(es.y + ed.y));
      w2 = __expf(lrelu(es.z + ed.z));
      w3 = __expf(lrelu(es.w + ed.w));
      z0 += w0; z1 += w1; z2 += w2; z3 += w3;
    }
    for (int j = 0; j < cnt; ++j) {
      int   sj = __shfl(s, j);
      float b0 = __shfl(w0, j), b1 = __shfl(w1, j);
      float b2 = __shfl(w2, j), b3 = __shfl(w3, j);
      float2 f = *(const float2*)(x + (size_t)sj * 128 + coff);
      a00 += b0 * f.x; a01 += b0 * f.y;
      a10 += b1 * f.x; a11 += b1 * f.y;
      a20 += b2 * f.x; a21 += b2 * f.y;
      a30 += b3 * f.x; a31 += b3 * f.y;
    }
  }
#pragma unroll
  for (int off = 1; off < 64; off <<= 1) {
    z0 += __shfl_xor(z0, off); z1 += __shfl_xor(z1, off);
    z2 += __shfl_xor(z2, off); z3 += __shfl_xor(z3, off);
  }
  float iz[4] = {1.f / z0, 1.f / z1, 1.f / z2, 1.f / z3};
  float va[4][2] = {{a00, a01}, {a10, a11}, {a20, a21}, {a30, a31}};
#pragma unroll
  for (int h = 0; h < 4; ++h) {
    size_t o = (size_t)n * 512 + h * 128 + coff;
    unsigned short h0, l0, h1, l1;
    split_bf(va[h][0] * iz[h], h0, l0);
    split_bf(va[h][1] * iz[h], h1, l1);
    g_aggx_h[o] = h0; g_aggx_h[o + 1] = h1;
    g_aggx_l[o] = l0; g_aggx_l[o + 1] = l1;
  }
}

// ------- bf16-split MFMA GEMM core: 128x128 tile, 256 thr / 4 waves ---------
// C[128,128] = A[128,K] @ B[K,128], A row-major hi/lo, B stored transposed
// [n][k] hi/lo. acc[i][j] = 16x16 tile (i=row tile, j=col tile) per wave.
// Layouts (m89/m91/m120-verified): A[m=lane&15][k=quad*8+j], B[k][n=lane&15],
// D[row=quad*4+reg][col=lane&15].
__device__ __forceinline__ void mfma_core(
    const unsigned short* __restrict__ Ah, const unsigned short* __restrict__ Al,
    int lda, const unsigned short* __restrict__ Bh,
    const unsigned short* __restrict__ Bl, int ldb,
    int row0, int M, int K, f4_t acc[4][4]) {
  __shared__ unsigned short As_h[128 * 40], As_l[128 * 40];
  __shared__ unsigned short Bs_h[128 * 40], Bs_l[128 * 40];
  const int t = threadIdx.x;
  const int lane = t & 63, w = t >> 6;
  const int wrow = w >> 1, wcol = w & 1;
  const int ln15 = lane & 15, qo = (lane >> 4) * 8;

  for (int ks = 0; ks < K; ks += 32) {
#pragma unroll
    for (int s = 0; s < 2; ++s) {
      int idx = s * 256 + t;
      int r = idx >> 2, kq = (idx & 3) << 3;
      uint4 z4 = make_uint4(0u, 0u, 0u, 0u);
      uint4 vah = z4, val = z4;
      if (row0 + r < M) {
        size_t ga = (size_t)(row0 + r) * lda + ks + kq;
        vah = *(const uint4*)&Ah[ga];
        val = *(const uint4*)&Al[ga];
      }
      *(uint4*)&As_h[r * 40 + kq] = vah;
      *(uint4*)&As_l[r * 40 + kq] = val;
      size_t gb = (size_t)r * ldb + ks + kq;
      *(uint4*)&Bs_h[r * 40 + kq] = *(const uint4*)&Bh[gb];
      *(uint4*)&Bs_l[r * 40 + kq] = *(const uint4*)&Bl[gb];
    }
    __syncthreads();
    bf8_t ah[4], al[4];
#pragma unroll
    for (int i = 0; i < 4; ++i) {
      int ma = (wrow * 64 + i * 16 + ln15) * 40 + qo;
      ah[i] = *(const bf8_t*)&As_h[ma];
      al[i] = *(const bf8_t*)&As_l[ma];
    }
#pragma unroll
    for (int j = 0; j < 4; ++j) {
      int nb = (wcol * 64 + j * 16 + ln15) * 40 + qo;
      bf8_t bh = *(const bf8_t*)&Bs_h[nb];
      bf8_t bl = *(const bf8_t*)&Bs_l[nb];
#pragma unroll
      for (int i = 0; i < 4; ++i) {
        acc[i][j] = __builtin_amdgcn_mfma_f32_16x16x32_bf16(ah[i], bh, acc[i][j], 0, 0, 0);
        acc[i][j] = __builtin_amdgcn_mfma_f32_16x16x32_bf16(al[i], bh, acc[i][j], 0, 0, 0);
        acc[i][j] = __builtin_amdgcn_mfma_f32_16x16x32_bf16(ah[i], bl, acc[i][j], 0, 0, 0);
      }
    }
    __syncthreads();
  }
}

// expand: per head h (blockIdx.z), h1b[:, h*128:+128] = relu(aggx_h @ W1_h + b1)
// emits bf16 hi/lo for gemm2 consumption
__global__ __launch_bounds__(256) void k_exp_mfma(const float* __restrict__ b1) {
  const int h = blockIdx.z;
  const int row0 = blockIdx.y * 128;
  f4_t acc[4][4] = {};
  mfma_core(g_aggx_h + h * 128, g_aggx_l + h * 128, 512,
            g_w1t_h + (size_t)h * 128 * 128, g_w1t_l + (size_t)h * 128 * 128, 128,
            row0, kN, 128, acc);
  const int lane = threadIdx.x & 63, w = threadIdx.x >> 6;
  const int wrow = w >> 1, wcol = w & 1;
  const int ln15 = lane & 15, q = lane >> 4;
#pragma unroll
  for (int j = 0; j < 4; ++j) {
    int col = wcol * 64 + j * 16 + ln15;          // 0..127 within head
    float bv = b1[h * 128 + col];
#pragma unroll
    for (int i = 0; i < 4; ++i) {
#pragma unroll
      for (int reg = 0; reg < 4; ++reg) {
        int r = row0 + wrow * 64 + i * 16 + q * 4 + reg;
        if (r < kN) {
          float v = fmaxf(acc[i][j][reg] + bv, 0.f);
          unsigned short hh, ll;
          split_bf(v, hh, ll);
          size_t o = (size_t)r * 512 + h * 128 + col;
          g_h1b_h[o] = hh; g_h1b_l[o] = ll;
        }
      }
    }
  }
}

// layer-2 GEMM, split-K=2: slice z covers K rows [z*256, z*256+256)
__global__ __launch_bounds__(256) void k_gemm2_mfma() {
  const int z = blockIdx.z;
  const int row0 = blockIdx.y * 128;
  f4_t acc[4][4] = {};
  mfma_core(g_h1b_h + z * 256, g_h1b_l + z * 256, 512,
            g_w2t_h + z * 256, g_w2t_l + z * 256, 512,
            row0, kN, 256, acc);
  const int lane = threadIdx.x & 63, w = threadIdx.x >> 6;
  const int wrow = w >> 1, wcol = w & 1;
  const int ln15 = lane & 15, q = lane >> 4;
  float* outp = g_h2p[z];
#pragma unroll
  for (int j = 0; j < 4; ++j) {
    int col = wcol * 64 + j * 16 + ln15;
#pragma unroll
    for (int i = 0; i < 4; ++i) {
#pragma unroll
      for (int reg = 0; reg < 4; ++reg) {
        int r = row0 + wrow * 64 + i * 16 + q * 4 + reg;
        if (r < kN) outp[(size_t)r * 128 + col] = acc[i][j][reg];
      }
    }
  }
}

// ---- fused partial-sum (2 slices) + layer-2 scores ----
__global__ __launch_bounds__(256) void k_scores2(const float* __restrict__ asrc,
                                                 const float* __restrict__ adst) {
  const int lane = threadIdx.x & 63;
  const int n = (blockIdx.x * 256 + threadIdx.x) >> 6;
  if (n >= kN) return;
  const size_t o = (size_t)n * 128;
  float v0 = g_h2p[0][o + lane]      + g_h2p[1][o + lane];
  float v1 = g_h2p[0][o + 64 + lane] + g_h2p[1][o + 64 + lane];
  g_h2[o + lane] = v0;
  g_h2[o + 64 + lane] = v1;
  float s = v0 * asrc[lane] + v1 * asrc[64 + lane];
  float d = v0 * adst[lane] + v1 * adst[64 + lane];
#pragma unroll
  for (int off = 32; off > 0; off >>= 1) {
    s += __shfl_down(s, off);
    d += __shfl_down(d, off);
  }
  if (lane == 0) { g_es2[n] = s; g_ed2[n] = d; }
}

// ---- layer-2 aggregation (H=1) + fused FC epilogue ----
__global__ __launch_bounds__(256) void k_agg2x(const float* __restrict__ b2,
    const float* __restrict__ fcw, const float* __restrict__ fcb,
    float* __restrict__ out) {
  const int lane = threadIdx.x & 63;
  const int n = (blockIdx.x * 256 + threadIdx.x) >> 6;
  if (n >= kN) return;
  const int beg = g_ptr[n], end = g_ptr[n + 1];
  const float ed = g_ed2[n];
  const int coff = lane * 2;
  float zp = 0.f, a0 = 0.f, a1 = 0.f;
  for (int base = beg; base < end; base += 64) {
    const int cnt = min(64, end - base);
    int s = 0; float w = 0.f;
    if (lane < cnt) {
      s = g_srcs[base + lane];
      w = __expf(lrelu(g_es2[s] + ed));
      zp += w;
    }
    for (int j = 0; j < cnt; ++j) {
      int   sj = __shfl(s, j);
      float wj = __shfl(w, j);
      float2 f = *(const float2*)(g_h2 + (size_t)sj * 128 + coff);
      a0 += wj * f.x; a1 += wj * f.y;
    }
  }
#pragma unroll
  for (int off = 1; off < 64; off <<= 1) zp += __shfl_xor(zp, off);
  float invz = 1.f / zp;
  float v0 = a0 * invz + b2[coff];
  float v1 = a1 * invz + b2[coff + 1];
  float s = v0 * fcw[coff] + v1 * fcw[coff + 1];
#pragma unroll
  for (int off = 1; off < 64; off <<= 1) s += __shfl_xor(s, off);
  if (lane == 0) out[n] = s + fcb[0];
}

extern "C" void kernel_launch(void* const* d_in, const int* in_sizes, int n_in,
                              void* d_out, int out_size, void* d_ws, size_t ws_size,
                              hipStream_t stream) {
  const float* x   = (const float*)d_in[0];
  const int*   ei  = (const int*)d_in[1];
  const float* W1  = (const float*)d_in[2];
  const float* a1s = (const float*)d_in[3];
  const float* a1d = (const float*)d_in[4];
  const float* b1  = (const float*)d_in[5];
  const float* W2  = (const float*)d_in[6];
  const float* a2s = (const float*)d_in[7];
  const float* a2d = (const float*)d_in[8];
  const float* b2  = (const float*)d_in[9];
  const float* fcw = (const float*)d_in[10];
  const float* fcb = (const float*)d_in[11];
  float* out = (float*)d_out;
  (void)d_ws; (void)ws_size; (void)in_sizes; (void)n_in; (void)out_size;

  // ---- CSR build (dst-sorted) + weight conversion ----
  k_zero_deg<<<(kN + 255) / 256, 256, 0, stream>>>();
  k_hist<<<(kEt + 255) / 256, 256, 0, stream>>>(ei);
  k_scan<<<1, 256, 0, stream>>>();
  k_scatter<<<(kEt + 255) / 256, 256, 0, stream>>>(ei);
  k_convw<<<512, 256, 0, stream>>>(W1, W2);

  // ---- layer 1 ----
  k_prep1<<<4, 256, 0, stream>>>(W1, a1s, a1d);
  k_scores1x<<<(kN * 64 + 255) / 256, 256, 0, stream>>>(x);
  k_agg1x<<<(kN * 64 + 255) / 256, 256, 0, stream>>>(x);
  dim3 ge(1, (kN + 127) / 128, 4);
  k_exp_mfma<<<ge, 256, 0, stream>>>(b1);

  // ---- layer 2 ----
  dim3 g2(1, (kN + 127) / 128, 2);
  k_gemm2_mfma<<<g2, 256, 0, stream>>>();
  k_scores2<<<(kN * 64 + 255) / 256, 256, 0, stream>>>(a2s, a2d);
  k_agg2x<<<(kN * 64 + 255) / 256, 256, 0, stream>>>(b2, fcw, fcb, out);
}

// Round 9
// 645.521 us; speedup vs baseline: 1.1514x; 1.0703x over previous
//
#include <hip/hip_runtime.h>
#include <cstdint>
#include <cstddef>

constexpr int kN   = 50000;          // nodes
constexpr int kE   = 800000;         // edges (without self loops)
constexpr int kEt  = kE + kN;        // edges + self loops
constexpr float kSlope = 0.2f;       // leaky relu slope

typedef __attribute__((ext_vector_type(8))) short bf8_t;   // 8 bf16 = 4 VGPRs
typedef __attribute__((ext_vector_type(4))) float f4_t;

// ---------------- static device workspace (d_ws unused) ---------------------
__device__ __align__(16) unsigned short g_aggx_h[(size_t)kN * 512]; // agg of x, bf16 hi
__device__ __align__(16) unsigned short g_aggx_l[(size_t)kN * 512]; // bf16 lo residual
__device__ __align__(16) unsigned short g_w1t_h[4 * 128 * 128];     // W1^T per head, hi
__device__ __align__(16) unsigned short g_w1t_l[4 * 128 * 128];
__device__ __align__(16) unsigned short g_w2t_h[128 * 512];         // W2^T, hi
__device__ __align__(16) unsigned short g_w2t_l[128 * 512];
__device__ __align__(16) float g_h2  [(size_t)kN * 128];  // layer-2 pre-agg features
__device__ __align__(16) float g_es1[kN * 4];
__device__ __align__(16) float g_ed1[kN * 4];
__device__ float g_es2[kN];
__device__ float g_ed2[kN];
__device__ __align__(16) float g_p1s[4 * 128];  // folded W1_h @ a1_src_h
__device__ __align__(16) float g_p1d[4 * 128];
// CSR by destination:
__device__ int g_deg[kN];
__device__ int g_ptr[kN + 1];
__device__ int g_cur[kN];
__device__ int g_srcs[kEt];

__device__ __forceinline__ float lrelu(float x) { return x > 0.f ? x : kSlope * x; }

// round-to-nearest-even f32 -> bf16 (returns bits; hi_f = value as f32)
__device__ __forceinline__ unsigned short f2bf(float v, float& hi_f) {
  unsigned u = __float_as_uint(v);
  unsigned r = (u + 0x7FFFu + ((u >> 16) & 1u)) & 0xFFFF0000u;
  hi_f = __uint_as_float(r);
  return (unsigned short)(r >> 16);
}
__device__ __forceinline__ void split_bf(float v, unsigned short& h, unsigned short& l) {
  float hf, lf;
  h = f2bf(v, hf);
  l = f2bf(v - hf, lf);
}

// ------------------------- CSR build ----------------------------------------
__global__ __launch_bounds__(256) void k_zero_deg() {
  int i = blockIdx.x * 256 + threadIdx.x;
  if (i < kN) g_deg[i] = 0;
}

__global__ __launch_bounds__(256) void k_hist(const int* __restrict__ ei) {
  int e = blockIdx.x * 256 + threadIdx.x;
  if (e >= kEt) return;
  int d = (e < kE) ? ei[kE + e] : e - kE;
  atomicAdd(&g_deg[d], 1);
}

__global__ __launch_bounds__(256) void k_scan() {
  __shared__ int s_sum[256];
  const int t = threadIdx.x;
  const int chunk = (kN + 255) / 256;
  const int lo = t * chunk, hi = min(lo + chunk, kN);
  int sum = 0;
  for (int i = lo; i < hi; ++i) sum += g_deg[i];
  s_sum[t] = sum;
  __syncthreads();
  for (int off = 1; off < 256; off <<= 1) {
    int xv = s_sum[t];
    int yv = (t >= off) ? s_sum[t - off] : 0;
    __syncthreads();
    s_sum[t] = xv + yv;
    __syncthreads();
  }
  int run = s_sum[t] - sum;
  for (int i = lo; i < hi; ++i) {
    g_ptr[i] = run;
    g_cur[i] = run;
    run += g_deg[i];
  }
  if (t == 255) g_ptr[kN] = run;
}

__global__ __launch_bounds__(256) void k_scatter(const int* __restrict__ ei) {
  int e = blockIdx.x * 256 + threadIdx.x;
  if (e >= kEt) return;
  int s, d;
  if (e < kE) { s = ei[e]; d = ei[kE + e]; } else { s = d = e - kE; }
  int slot = atomicAdd(&g_cur[d], 1);
  g_srcs[slot] = s;
}

// ---- weight conversion: W1 -> per-head W1T hi/lo, W2 -> W2T hi/lo ----------
__global__ __launch_bounds__(256) void k_convw(const float* __restrict__ W1,
                                               const float* __restrict__ W2) {
  int gid = blockIdx.x * 256 + threadIdx.x;   // 0..131071
  if (gid < 65536) {
    int h = gid >> 14, rem = gid & 16383;
    int c = rem >> 7, j = rem & 127;          // read coalesced in j
    float v = W1[(size_t)c * 512 + h * 128 + j];
    unsigned short hh, ll;
    split_bf(v, hh, ll);
    size_t o = ((size_t)h * 128 + j) * 128 + c;
    g_w1t_h[o] = hh; g_w1t_l[o] = ll;
  } else {
    int g2 = gid - 65536;
    int k = g2 >> 7, j = g2 & 127;            // read coalesced in j
    float v = W2[(size_t)k * 128 + j];
    unsigned short hh, ll;
    split_bf(v, hh, ll);
    size_t o = (size_t)j * 512 + k;
    g_w2t_h[o] = hh; g_w2t_l[o] = ll;
  }
}

// ---- fold attention vectors through W1 ----
__global__ __launch_bounds__(256) void k_prep1(const float* __restrict__ W1,
    const float* __restrict__ a1s, const float* __restrict__ a1d) {
  int gid = blockIdx.x * 256 + threadIdx.x;
  if (gid >= 1024) return;
  int which = gid >> 9, idx = gid & 511;
  int h = idx >> 7, k = idx & 127;
  const float* a = which ? a1d : a1s;
  const float* wrow = W1 + (size_t)k * 512 + h * 128;
  float s = 0.f;
#pragma unroll 8
  for (int c = 0; c < 128; ++c) s += wrow[c] * a[h * 128 + c];
  (which ? g_p1d : g_p1s)[idx] = s;
}

// ---- layer-1 scores directly from x ----
__global__ __launch_bounds__(256) void k_scores1x(const float* __restrict__ x) {
  const int lane = threadIdx.x & 63;
  const int n = (blockIdx.x * 256 + threadIdx.x) >> 6;
  if (n >= kN) return;
  float x0 = x[(size_t)n * 128 + lane];
  float x1 = x[(size_t)n * 128 + 64 + lane];
  float s[4], d[4];
#pragma unroll
  for (int h = 0; h < 4; ++h) {
    s[h] = x0 * g_p1s[h * 128 + lane] + x1 * g_p1s[h * 128 + 64 + lane];
    d[h] = x0 * g_p1d[h * 128 + lane] + x1 * g_p1d[h * 128 + 64 + lane];
  }
#pragma unroll
  for (int off = 32; off > 0; off >>= 1) {
#pragma unroll
    for (int h = 0; h < 4; ++h) {
      s[h] += __shfl_down(s[h], off);
      d[h] += __shfl_down(d[h], off);
    }
  }
  if (lane == 0) {
    *(float4*)(g_es1 + (size_t)n * 4) = make_float4(s[0], s[1], s[2], s[3]);
    *(float4*)(g_ed1 + (size_t)n * 4) = make_float4(d[0], d[1], d[2], d[3]);
  }
}

// ---- layer-1 aggregation of x rows, normalized; emits bf16 hi/lo ----
__global__ __launch_bounds__(256) void k_agg1x(const float* __restrict__ x) {
  const int lane = threadIdx.x & 63;
  const int n = (blockIdx.x * 256 + threadIdx.x) >> 6;
  if (n >= kN) return;
  const int beg = g_ptr[n], end = g_ptr[n + 1];
  const float4 ed = *(const float4*)(g_ed1 + (size_t)n * 4);
  const int coff = lane * 2;
  float z0 = 0.f, z1 = 0.f, z2 = 0.f, z3 = 0.f;
  float a00 = 0.f, a01 = 0.f, a10 = 0.f, a11 = 0.f;
  float a20 = 0.f, a21 = 0.f, a30 = 0.f, a31 = 0.f;
  for (int base = beg; base < end; base += 64) {
    const int cnt = min(64, end - base);
    int s = 0;
    float w0 = 0.f, w1 = 0.f, w2 = 0.f, w3 = 0.f;
    if (lane < cnt) {
      s = g_srcs[base + lane];
      float4 es = *(const float4*)(g_es1 + (size_t)s * 4);
      w0 = __expf(lrelu(es.x + ed.x));
      w1 = __expf(lrelu(es.y + ed.y));
      w2 = __expf(lrelu(es.z + ed.z));
      w3 = __expf(lrelu(es.w + ed.w));
      z0 += w0; z1 += w1; z2 += w2; z3 += w3;
    }
    for (int j = 0; j < cnt; ++j) {
      int   sj = __shfl(s, j);
      float b0 = __shfl(w0, j), b1 = __shfl(w1, j);
      float b2 = __shfl(w2, j), b3 = __shfl(w3, j);
      float2 f = *(const float2*)(x + (size_t)sj * 128 + coff);
      a00 += b0 * f.x; a01 += b0 * f.y;
      a10 += b1 * f.x; a11 += b1 * f.y;
      a20 += b2 * f.x; a21 += b2 * f.y;
      a30 += b3 * f.x; a31 += b3 * f.y;
    }
  }
#pragma unroll
  for (int off = 1; off < 64; off <<= 1) {
    z0 += __shfl_xor(z0, off); z1 += __shfl_xor(z1, off);
    z2 += __shfl_xor(z2, off); z3 += __shfl_xor(z3, off);
  }
  float iz[4] = {1.f / z0, 1.f / z1, 1.f / z2, 1.f / z3};
  float va[4][2] = {{a00, a01}, {a10, a11}, {a20, a21}, {a30, a31}};
#pragma unroll
  for (int h = 0; h < 4; ++h) {
    size_t o = (size_t)n * 512 + h * 128 + coff;
    unsigned short h0, l0, h1, l1;
    split_bf(va[h][0] * iz[h], h0, l0);
    split_bf(va[h][1] * iz[h], h1, l1);
    g_aggx_h[o] = h0; g_aggx_h[o + 1] = h1;
    g_aggx_l[o] = l0; g_aggx_l[o + 1] = l1;
  }
}

// ------- fused layer-1 expand + layer-2 GEMM (h1 never leaves the CU) -------
// Per 128-row tile, for each head h: h1_h = relu(aggx_h @ W1_h + b1_h) via
// MFMA (split-bf16 3-pass), round-trip h1_h through LDS as bf16 hi/lo, then
// h2 += h1_h @ W2_h. W1^T/W2^T fragments are read directly from global (L2).
// Layouts (verified r8): A[m=lane&15][k=quad*8+e], B[n][k] store, D[row=quad*4+reg][col=lane&15].
__global__ __launch_bounds__(256) void k_fused(const float* __restrict__ b1) {
  __shared__ unsigned short smem[18432];    // 36864 B
  unsigned short* S1h = smem;               // expand A staging [128][40]
  unsigned short* S1l = smem + 5120;
  unsigned short* Hh  = smem;               // h1 chunk [128 rows][72] (64 cols + pad)
  unsigned short* Hl  = smem + 9216;        // (overlaps S1 — phases barrier-separated)
  const int t = threadIdx.x;
  const int lane = t & 63, w = t >> 6;
  const int wrow = w >> 1, wcol = w & 1;
  const int ln15 = lane & 15, q = lane >> 4, qo = q * 8;
  const int row0 = blockIdx.y * 128;

  f4_t h2acc[4][4] = {};
#pragma unroll 1
  for (int h = 0; h < 4; ++h) {
    // ---------------- phase 1: h1acc = aggx_h @ W1_h ----------------
    f4_t h1acc[4][4] = {};
#pragma unroll 1
    for (int ks = 0; ks < 128; ks += 32) {
      __syncthreads();   // protect S1 (overlaps H) from previous readers
#pragma unroll
      for (int s = 0; s < 2; ++s) {
        int idx = s * 256 + t;
        int r = idx >> 2, kq = (idx & 3) << 3;
        uint4 vh = make_uint4(0u, 0u, 0u, 0u), vl = vh;
        if (row0 + r < kN) {
          size_t ga = (size_t)(row0 + r) * 512 + h * 128 + ks + kq;
          vh = *(const uint4*)&g_aggx_h[ga];
          vl = *(const uint4*)&g_aggx_l[ga];
        }
        *(uint4*)&S1h[r * 40 + kq] = vh;
        *(uint4*)&S1l[r * 40 + kq] = vl;
      }
      __syncthreads();
      bf8_t ah[4], al[4];
#pragma unroll
      for (int i = 0; i < 4; ++i) {
        int ma = (wrow * 64 + i * 16 + ln15) * 40 + qo;
        ah[i] = *(const bf8_t*)&S1h[ma];
        al[i] = *(const bf8_t*)&S1l[ma];
      }
#pragma unroll
      for (int j = 0; j < 4; ++j) {
        size_t gb = ((size_t)h * 128 + wcol * 64 + j * 16 + ln15) * 128 + ks + qo;
        bf8_t bh = *(const bf8_t*)&g_w1t_h[gb];
        bf8_t bl = *(const bf8_t*)&g_w1t_l[gb];
#pragma unroll
        for (int i = 0; i < 4; ++i)
          h1acc[i][j] = __builtin_amdgcn_mfma_f32_16x16x32_bf16(ah[i], bh, h1acc[i][j], 0, 0, 0);
#pragma unroll
        for (int i = 0; i < 4; ++i)
          h1acc[i][j] = __builtin_amdgcn_mfma_f32_16x16x32_bf16(al[i], bh, h1acc[i][j], 0, 0, 0);
#pragma unroll
        for (int i = 0; i < 4; ++i)
          h1acc[i][j] = __builtin_amdgcn_mfma_f32_16x16x32_bf16(ah[i], bl, h1acc[i][j], 0, 0, 0);
      }
    }
    // ---------------- phase 2: bias + relu + split-bf16 ----------------
    unsigned pk[4][4][4];
#pragma unroll
    for (int j = 0; j < 4; ++j) {
      float bv = b1[h * 128 + wcol * 64 + j * 16 + ln15];
#pragma unroll
      for (int i = 0; i < 4; ++i)
#pragma unroll
        for (int reg = 0; reg < 4; ++reg) {
          float v = fmaxf(h1acc[i][j][reg] + bv, 0.f);
          unsigned short hh, ll;
          split_bf(v, hh, ll);
          pk[i][j][reg] = ((unsigned)hh << 16) | ll;
        }
    }
    // ---------------- phase 3: h2 += h1_h @ W2_h (two 64-col chunks) --------
#pragma unroll 1
    for (int cc = 0; cc < 2; ++cc) {
      __syncthreads();   // protect H overwrite from previous readers
      if (wcol == cc) {
#pragma unroll
        for (int i = 0; i < 4; ++i)
#pragma unroll
          for (int j = 0; j < 4; ++j)
#pragma unroll
            for (int reg = 0; reg < 4; ++reg) {
              int rl = wrow * 64 + i * 16 + q * 4 + reg;
              int cl = j * 16 + ln15;
              Hh[rl * 72 + cl] = (unsigned short)(pk[i][j][reg] >> 16);
              Hl[rl * 72 + cl] = (unsigned short)(pk[i][j][reg] & 0xFFFFu);
            }
      }
      __syncthreads();
#pragma unroll 1
      for (int kc = 0; kc < 64; kc += 32) {
        bf8_t ah[4], al[4];
#pragma unroll
        for (int i = 0; i < 4; ++i) {
          int ma = (wrow * 64 + i * 16 + ln15) * 72 + kc + qo;
          ah[i] = *(const bf8_t*)&Hh[ma];
          al[i] = *(const bf8_t*)&Hl[ma];
        }
#pragma unroll
        for (int j = 0; j < 4; ++j) {
          size_t gb = (size_t)(wcol * 64 + j * 16 + ln15) * 512 + h * 128 + cc * 64 + kc + qo;
          bf8_t bh = *(const bf8_t*)&g_w2t_h[gb];
          bf8_t bl = *(const bf8_t*)&g_w2t_l[gb];
#pragma unroll
          for (int i = 0; i < 4; ++i)
            h2acc[i][j] = __builtin_amdgcn_mfma_f32_16x16x32_bf16(ah[i], bh, h2acc[i][j], 0, 0, 0);
#pragma unroll
          for (int i = 0; i < 4; ++i)
            h2acc[i][j] = __builtin_amdgcn_mfma_f32_16x16x32_bf16(al[i], bh, h2acc[i][j], 0, 0, 0);
#pragma unroll
          for (int i = 0; i < 4; ++i)
            h2acc[i][j] = __builtin_amdgcn_mfma_f32_16x16x32_bf16(ah[i], bl, h2acc[i][j], 0, 0, 0);
        }
      }
    }
  }
  // ---------------- epilogue: write h2 (f32) ----------------
#pragma unroll
  for (int j = 0; j < 4; ++j) {
    int col = wcol * 64 + j * 16 + ln15;
#pragma unroll
    for (int i = 0; i < 4; ++i)
#pragma unroll
      for (int reg = 0; reg < 4; ++reg) {
        int r = row0 + wrow * 64 + i * 16 + q * 4 + reg;
        if (r < kN) g_h2[(size_t)r * 128 + col] = h2acc[i][j][reg];
      }
  }
}

// ---- layer-2 scores (reads h2 directly) ----
__global__ __launch_bounds__(256) void k_scores2(const float* __restrict__ asrc,
                                                 const float* __restrict__ adst) {
  const int lane = threadIdx.x & 63;
  const int n = (blockIdx.x * 256 + threadIdx.x) >> 6;
  if (n >= kN) return;
  const size_t o = (size_t)n * 128;
  float v0 = g_h2[o + lane];
  float v1 = g_h2[o + 64 + lane];
  float s = v0 * asrc[lane] + v1 * asrc[64 + lane];
  float d = v0 * adst[lane] + v1 * adst[64 + lane];
#pragma unroll
  for (int off = 32; off > 0; off >>= 1) {
    s += __shfl_down(s, off);
    d += __shfl_down(d, off);
  }
  if (lane == 0) { g_es2[n] = s; g_ed2[n] = d; }
}

// ---- layer-2 aggregation (H=1) + fused FC epilogue ----
__global__ __launch_bounds__(256) void k_agg2x(const float* __restrict__ b2,
    const float* __restrict__ fcw, const float* __restrict__ fcb,
    float* __restrict__ out) {
  const int lane = threadIdx.x & 63;
  const int n = (blockIdx.x * 256 + threadIdx.x) >> 6;
  if (n >= kN) return;
  const int beg = g_ptr[n], end = g_ptr[n + 1];
  const float ed = g_ed2[n];
  const int coff = lane * 2;
  float zp = 0.f, a0 = 0.f, a1 = 0.f;
  for (int base = beg; base < end; base += 64) {
    const int cnt = min(64, end - base);
    int s = 0; float w = 0.f;
    if (lane < cnt) {
      s = g_srcs[base + lane];
      w = __expf(lrelu(g_es2[s] + ed));
      zp += w;
    }
    for (int j = 0; j < cnt; ++j) {
      int   sj = __shfl(s, j);
      float wj = __shfl(w, j);
      float2 f = *(const float2*)(g_h2 + (size_t)sj * 128 + coff);
      a0 += wj * f.x; a1 += wj * f.y;
    }
  }
#pragma unroll
  for (int off = 1; off < 64; off <<= 1) zp += __shfl_xor(zp, off);
  float invz = 1.f / zp;
  float v0 = a0 * invz + b2[coff];
  float v1 = a1 * invz + b2[coff + 1];
  float s = v0 * fcw[coff] + v1 * fcw[coff + 1];
#pragma unroll
  for (int off = 1; off < 64; off <<= 1) s += __shfl_xor(s, off);
  if (lane == 0) out[n] = s + fcb[0];
}

extern "C" void kernel_launch(void* const* d_in, const int* in_sizes, int n_in,
                              void* d_out, int out_size, void* d_ws, size_t ws_size,
                              hipStream_t stream) {
  const float* x   = (const float*)d_in[0];
  const int*   ei  = (const int*)d_in[1];
  const float* W1  = (const float*)d_in[2];
  const float* a1s = (const float*)d_in[3];
  const float* a1d = (const float*)d_in[4];
  const float* b1  = (const float*)d_in[5];
  const float* W2  = (const float*)d_in[6];
  const float* a2s = (const float*)d_in[7];
  const float* a2d = (const float*)d_in[8];
  const float* b2  = (const float*)d_in[9];
  const float* fcw = (const float*)d_in[10];
  const float* fcb = (const float*)d_in[11];
  float* out = (float*)d_out;
  (void)d_ws; (void)ws_size; (void)in_sizes; (void)n_in; (void)out_size;

  // ---- CSR build (dst-sorted) + weight conversion ----
  k_zero_deg<<<(kN + 255) / 256, 256, 0, stream>>>();
  k_hist<<<(kEt + 255) / 256, 256, 0, stream>>>(ei);
  k_scan<<<1, 256, 0, stream>>>();
  k_scatter<<<(kEt + 255) / 256, 256, 0, stream>>>(ei);
  k_convw<<<512, 256, 0, stream>>>(W1, W2);

  // ---- layer 1 ----
  k_prep1<<<4, 256, 0, stream>>>(W1, a1s, a1d);
  k_scores1x<<<(kN * 64 + 255) / 256, 256, 0, stream>>>(x);
  k_agg1x<<<(kN * 64 + 255) / 256, 256, 0, stream>>>(x);

  // ---- fused expand + layer-2 GEMM ----
  dim3 gf(1, (kN + 127) / 128, 1);
  k_fused<<<gf, 256, 0, stream>>>(b1);

  // ---- layer 2 tail ----
  k_scores2<<<(kN * 64 + 255) / 256, 256, 0, stream>>>(a2s, a2d);
  k_agg2x<<<(kN * 64 + 255) / 256, 256, 0, stream>>>(b2, fcw, fcb, out);
}

// Round 10
// 640.754 us; speedup vs baseline: 1.1600x; 1.0074x over previous
//
#include <hip/hip_runtime.h>
#include <cstdint>
#include <cstddef>

constexpr int kN   = 50000;          // nodes
constexpr int kE   = 800000;         // edges (without self loops)
constexpr int kEt  = kE + kN;        // edges + self loops
constexpr float kSlope = 0.2f;       // leaky relu slope

typedef __attribute__((ext_vector_type(8))) short bf8_t;   // 8 bf16 = 4 VGPRs
typedef __attribute__((ext_vector_type(4))) float f4_t;

// ---------------- static device workspace (d_ws unused) ---------------------
__device__ __align__(16) unsigned short g_aggx_h[(size_t)kN * 512]; // agg of x, bf16 hi
__device__ __align__(16) unsigned short g_aggx_l[(size_t)kN * 512]; // bf16 lo residual
__device__ __align__(16) unsigned short g_w1t_h[4 * 128 * 128];     // W1^T per head, hi
__device__ __align__(16) unsigned short g_w1t_l[4 * 128 * 128];
__device__ __align__(16) unsigned short g_w2t_h[128 * 512];         // W2^T, hi
__device__ __align__(16) unsigned short g_w2t_l[128 * 512];
__device__ __align__(16) float g_h2  [(size_t)kN * 128];  // layer-2 pre-agg features
__device__ __align__(16) float g_h2p [2][(size_t)kN * 128]; // head-pair partials
__device__ __align__(16) float g_es1[kN * 4];
__device__ __align__(16) float g_ed1[kN * 4];
__device__ float g_es2[kN];
__device__ float g_ed2[kN];
__device__ __align__(16) float g_p1s[4 * 128];  // folded W1_h @ a1_src_h
__device__ __align__(16) float g_p1d[4 * 128];
// CSR by destination:
__device__ int g_deg[kN];
__device__ int g_ptr[kN + 1];
__device__ int g_cur[kN];
__device__ int g_srcs[kEt];

__device__ __forceinline__ float lrelu(float x) { return x > 0.f ? x : kSlope * x; }

// round-to-nearest-even f32 -> bf16 (returns bits; hi_f = value as f32)
__device__ __forceinline__ unsigned short f2bf(float v, float& hi_f) {
  unsigned u = __float_as_uint(v);
  unsigned r = (u + 0x7FFFu + ((u >> 16) & 1u)) & 0xFFFF0000u;
  hi_f = __uint_as_float(r);
  return (unsigned short)(r >> 16);
}
__device__ __forceinline__ void split_bf(float v, unsigned short& h, unsigned short& l) {
  float hf, lf;
  h = f2bf(v, hf);
  l = f2bf(v - hf, lf);
}

// ------------------------- CSR build ----------------------------------------
__global__ __launch_bounds__(256) void k_zero_deg() {
  int i = blockIdx.x * 256 + threadIdx.x;
  if (i < kN) g_deg[i] = 0;
}

__global__ __launch_bounds__(256) void k_hist(const int* __restrict__ ei) {
  int e = blockIdx.x * 256 + threadIdx.x;
  if (e >= kEt) return;
  int d = (e < kE) ? ei[kE + e] : e - kE;
  atomicAdd(&g_deg[d], 1);
}

__global__ __launch_bounds__(256) void k_scan() {
  __shared__ int s_sum[256];
  const int t = threadIdx.x;
  const int chunk = (kN + 255) / 256;
  const int lo = t * chunk, hi = min(lo + chunk, kN);
  int sum = 0;
  for (int i = lo; i < hi; ++i) sum += g_deg[i];
  s_sum[t] = sum;
  __syncthreads();
  for (int off = 1; off < 256; off <<= 1) {
    int xv = s_sum[t];
    int yv = (t >= off) ? s_sum[t - off] : 0;
    __syncthreads();
    s_sum[t] = xv + yv;
    __syncthreads();
  }
  int run = s_sum[t] - sum;
  for (int i = lo; i < hi; ++i) {
    g_ptr[i] = run;
    g_cur[i] = run;
    run += g_deg[i];
  }
  if (t == 255) g_ptr[kN] = run;
}

__global__ __launch_bounds__(256) void k_scatter(const int* __restrict__ ei) {
  int e = blockIdx.x * 256 + threadIdx.x;
  if (e >= kEt) return;
  int s, d;
  if (e < kE) { s = ei[e]; d = ei[kE + e]; } else { s = d = e - kE; }
  int slot = atomicAdd(&g_cur[d], 1);
  g_srcs[slot] = s;
}

// ---- weight conversion: W1 -> per-head W1T hi/lo, W2 -> W2T hi/lo ----------
__global__ __launch_bounds__(256) void k_convw(const float* __restrict__ W1,
                                               const float* __restrict__ W2) {
  int gid = blockIdx.x * 256 + threadIdx.x;   // 0..131071
  if (gid < 65536) {
    int h = gid >> 14, rem = gid & 16383;
    int c = rem >> 7, j = rem & 127;          // read coalesced in j
    float v = W1[(size_t)c * 512 + h * 128 + j];
    unsigned short hh, ll;
    split_bf(v, hh, ll);
    size_t o = ((size_t)h * 128 + j) * 128 + c;
    g_w1t_h[o] = hh; g_w1t_l[o] = ll;
  } else {
    int g2 = gid - 65536;
    int k = g2 >> 7, j = g2 & 127;            // read coalesced in j
    float v = W2[(size_t)k * 128 + j];
    unsigned short hh, ll;
    split_bf(v, hh, ll);
    size_t o = (size_t)j * 512 + k;
    g_w2t_h[o] = hh; g_w2t_l[o] = ll;
  }
}

// ---- fold attention vectors through W1 ----
__global__ __launch_bounds__(256) void k_prep1(const float* __restrict__ W1,
    const float* __restrict__ a1s, const float* __restrict__ a1d) {
  int gid = blockIdx.x * 256 + threadIdx.x;
  if (gid >= 1024) return;
  int which = gid >> 9, idx = gid & 511;
  int h = idx >> 7, k = idx & 127;
  const float* a = which ? a1d : a1s;
  const float* wrow = W1 + (size_t)k * 512 + h * 128;
  float s = 0.f;
#pragma unroll 8
  for (int c = 0; c < 128; ++c) s += wrow[c] * a[h * 128 + c];
  (which ? g_p1d : g_p1s)[idx] = s;
}

// ---- layer-1 scores directly from x ----
__global__ __launch_bounds__(256) void k_scores1x(const float* __restrict__ x) {
  const int lane = threadIdx.x & 63;
  const int n = (blockIdx.x * 256 + threadIdx.x) >> 6;
  if (n >= kN) return;
  float x0 = x[(size_t)n * 128 + lane];
  float x1 = x[(size_t)n * 128 + 64 + lane];
  float s[4], d[4];
#pragma unroll
  for (int h = 0; h < 4; ++h) {
    s[h] = x0 * g_p1s[h * 128 + lane] + x1 * g_p1s[h * 128 + 64 + lane];
    d[h] = x0 * g_p1d[h * 128 + lane] + x1 * g_p1d[h * 128 + 64 + lane];
  }
#pragma unroll
  for (int off = 32; off > 0; off >>= 1) {
#pragma unroll
    for (int h = 0; h < 4; ++h) {
      s[h] += __shfl_down(s[h], off);
      d[h] += __shfl_down(d[h], off);
    }
  }
  if (lane == 0) {
    *(float4*)(g_es1 + (size_t)n * 4) = make_float4(s[0], s[1], s[2], s[3]);
    *(float4*)(g_ed1 + (size_t)n * 4) = make_float4(d[0], d[1], d[2], d[3]);
  }
}

// ---- layer-1 aggregation: 2 edges/iter, float4 gathers; emits bf16 hi/lo ---
__global__ __launch_bounds__(256) void k_agg1x(const float* __restrict__ x) {
  const int lane = threadIdx.x & 63;
  const int n = (blockIdx.x * 256 + threadIdx.x) >> 6;
  if (n >= kN) return;
  const int beg = g_ptr[n], end = g_ptr[n + 1];
  const float4 ed = *(const float4*)(g_ed1 + (size_t)n * 4);
  const int half = lane >> 5, hl = lane & 31;
  float z0 = 0.f, z1 = 0.f, z2 = 0.f, z3 = 0.f;
  float a0[4] = {}, a1[4] = {}, a2[4] = {}, a3[4] = {};
  for (int base = beg; base < end; base += 64) {
    const int cnt = min(64, end - base);
    int s = 0;
    float w0 = 0.f, w1 = 0.f, w2 = 0.f, w3 = 0.f;
    if (lane < cnt) {
      s = g_srcs[base + lane];
      float4 es = *(const float4*)(g_es1 + (size_t)s * 4);
      w0 = __expf(lrelu(es.x + ed.x));
      w1 = __expf(lrelu(es.y + ed.y));
      w2 = __expf(lrelu(es.z + ed.z));
      w3 = __expf(lrelu(es.w + ed.w));
      z0 += w0; z1 += w1; z2 += w2; z3 += w3;
    }
    const int pairs = (cnt + 1) >> 1;
    for (int p = 0; p < pairs; ++p) {
      int ei = 2 * p + half;             // if ei >= cnt, that lane's w's are 0
      int   sj = __shfl(s, ei);
      float b0 = __shfl(w0, ei), b1 = __shfl(w1, ei);
      float b2 = __shfl(w2, ei), b3 = __shfl(w3, ei);
      float4 f = *(const float4*)(x + (size_t)sj * 128 + hl * 4);
      a0[0] += b0 * f.x; a0[1] += b0 * f.y; a0[2] += b0 * f.z; a0[3] += b0 * f.w;
      a1[0] += b1 * f.x; a1[1] += b1 * f.y; a1[2] += b1 * f.z; a1[3] += b1 * f.w;
      a2[0] += b2 * f.x; a2[1] += b2 * f.y; a2[2] += b2 * f.z; a2[3] += b2 * f.w;
      a3[0] += b3 * f.x; a3[1] += b3 * f.y; a3[2] += b3 * f.z; a3[3] += b3 * f.w;
    }
  }
  // cross-half feature reduce
#pragma unroll
  for (int k = 0; k < 4; ++k) {
    a0[k] += __shfl_xor(a0[k], 32);
    a1[k] += __shfl_xor(a1[k], 32);
    a2[k] += __shfl_xor(a2[k], 32);
    a3[k] += __shfl_xor(a3[k], 32);
  }
  // z full reduce
#pragma unroll
  for (int off = 1; off < 64; off <<= 1) {
    z0 += __shfl_xor(z0, off); z1 += __shfl_xor(z1, off);
    z2 += __shfl_xor(z2, off); z3 += __shfl_xor(z3, off);
  }
  // half 0 writes heads 0,1; half 1 writes heads 2,3
  float vx[4], vy[4];
  float izx, izy;
  if (half == 0) {
    izx = 1.f / z0; izy = 1.f / z1;
#pragma unroll
    for (int k = 0; k < 4; ++k) { vx[k] = a0[k]; vy[k] = a1[k]; }
  } else {
    izx = 1.f / z2; izy = 1.f / z3;
#pragma unroll
    for (int k = 0; k < 4; ++k) { vx[k] = a2[k]; vy[k] = a3[k]; }
  }
  const int hx = half * 2, hy = half * 2 + 1;
  ushort4 xh, xl, yh, yl;
  split_bf(vx[0] * izx, xh.x, xl.x); split_bf(vx[1] * izx, xh.y, xl.y);
  split_bf(vx[2] * izx, xh.z, xl.z); split_bf(vx[3] * izx, xh.w, xl.w);
  split_bf(vy[0] * izy, yh.x, yl.x); split_bf(vy[1] * izy, yh.y, yl.y);
  split_bf(vy[2] * izy, yh.z, yl.z); split_bf(vy[3] * izy, yh.w, yl.w);
  size_t ox = (size_t)n * 512 + hx * 128 + hl * 4;
  size_t oy = (size_t)n * 512 + hy * 128 + hl * 4;
  *(ushort4*)(g_aggx_h + ox) = xh; *(ushort4*)(g_aggx_l + ox) = xl;
  *(ushort4*)(g_aggx_h + oy) = yh; *(ushort4*)(g_aggx_l + oy) = yl;
}

// ------- fused layer-1 expand + layer-2 GEMM (h1 never leaves the CU) -------
// blockIdx.z = head pair (2 heads per block); writes partial h2 to g_h2p[z].
__global__ __launch_bounds__(256) void k_fused(const float* __restrict__ b1) {
  __shared__ unsigned short smem[18432];    // 36864 B
  unsigned short* S1h = smem;               // expand A staging [128][40]
  unsigned short* S1l = smem + 5120;
  unsigned short* Hh  = smem;               // h1 chunk [128 rows][72]
  unsigned short* Hl  = smem + 9216;        // (overlaps S1 — barrier-separated)
  const int t = threadIdx.x;
  const int lane = t & 63, w = t >> 6;
  const int wrow = w >> 1, wcol = w & 1;
  const int ln15 = lane & 15, q = lane >> 4, qo = q * 8;
  const int row0 = blockIdx.y * 128;
  const int zp = blockIdx.z;

  f4_t h2acc[4][4] = {};
#pragma unroll 1
  for (int hh = 0; hh < 2; ++hh) {
    const int h = zp * 2 + hh;
    // ---------------- phase 1: h1acc = aggx_h @ W1_h ----------------
    f4_t h1acc[4][4] = {};
#pragma unroll 1
    for (int ks = 0; ks < 128; ks += 32) {
      __syncthreads();   // protect S1 (overlaps H) from previous readers
#pragma unroll
      for (int s = 0; s < 2; ++s) {
        int idx = s * 256 + t;
        int r = idx >> 2, kq = (idx & 3) << 3;
        uint4 vh = make_uint4(0u, 0u, 0u, 0u), vl = vh;
        if (row0 + r < kN) {
          size_t ga = (size_t)(row0 + r) * 512 + h * 128 + ks + kq;
          vh = *(const uint4*)&g_aggx_h[ga];
          vl = *(const uint4*)&g_aggx_l[ga];
        }
        *(uint4*)&S1h[r * 40 + kq] = vh;
        *(uint4*)&S1l[r * 40 + kq] = vl;
      }
      __syncthreads();
      bf8_t ah[4], al[4];
#pragma unroll
      for (int i = 0; i < 4; ++i) {
        int ma = (wrow * 64 + i * 16 + ln15) * 40 + qo;
        ah[i] = *(const bf8_t*)&S1h[ma];
        al[i] = *(const bf8_t*)&S1l[ma];
      }
#pragma unroll
      for (int j = 0; j < 4; ++j) {
        size_t gb = ((size_t)h * 128 + wcol * 64 + j * 16 + ln15) * 128 + ks + qo;
        bf8_t bh = *(const bf8_t*)&g_w1t_h[gb];
        bf8_t bl = *(const bf8_t*)&g_w1t_l[gb];
#pragma unroll
        for (int i = 0; i < 4; ++i)
          h1acc[i][j] = __builtin_amdgcn_mfma_f32_16x16x32_bf16(ah[i], bh, h1acc[i][j], 0, 0, 0);
#pragma unroll
        for (int i = 0; i < 4; ++i)
          h1acc[i][j] = __builtin_amdgcn_mfma_f32_16x16x32_bf16(al[i], bh, h1acc[i][j], 0, 0, 0);
#pragma unroll
        for (int i = 0; i < 4; ++i)
          h1acc[i][j] = __builtin_amdgcn_mfma_f32_16x16x32_bf16(ah[i], bl, h1acc[i][j], 0, 0, 0);
      }
    }
    // ---------------- phase 2: bias + relu + split-bf16 ----------------
    unsigned pk[4][4][4];
#pragma unroll
    for (int j = 0; j < 4; ++j) {
      float bv = b1[h * 128 + wcol * 64 + j * 16 + ln15];
#pragma unroll
      for (int i = 0; i < 4; ++i)
#pragma unroll
        for (int reg = 0; reg < 4; ++reg) {
          float v = fmaxf(h1acc[i][j][reg] + bv, 0.f);
          unsigned short hb, lb;
          split_bf(v, hb, lb);
          pk[i][j][reg] = ((unsigned)hb << 16) | lb;
        }
    }
    // ---------------- phase 3: h2 += h1_h @ W2_h (two 64-col chunks) --------
#pragma unroll 1
    for (int cc = 0; cc < 2; ++cc) {
      __syncthreads();   // protect H overwrite from previous readers
      if (wcol == cc) {
#pragma unroll
        for (int i = 0; i < 4; ++i)
#pragma unroll
          for (int j = 0; j < 4; ++j)
#pragma unroll
            for (int reg = 0; reg < 4; ++reg) {
              int rl = wrow * 64 + i * 16 + q * 4 + reg;
              int cl = j * 16 + ln15;
              Hh[rl * 72 + cl] = (unsigned short)(pk[i][j][reg] >> 16);
              Hl[rl * 72 + cl] = (unsigned short)(pk[i][j][reg] & 0xFFFFu);
            }
      }
      __syncthreads();
#pragma unroll 1
      for (int kc = 0; kc < 64; kc += 32) {
        bf8_t ah[4], al[4];
#pragma unroll
        for (int i = 0; i < 4; ++i) {
          int ma = (wrow * 64 + i * 16 + ln15) * 72 + kc + qo;
          ah[i] = *(const bf8_t*)&Hh[ma];
          al[i] = *(const bf8_t*)&Hl[ma];
        }
#pragma unroll
        for (int j = 0; j < 4; ++j) {
          size_t gb = (size_t)(wcol * 64 + j * 16 + ln15) * 512 + h * 128 + cc * 64 + kc + qo;
          bf8_t bh = *(const bf8_t*)&g_w2t_h[gb];
          bf8_t bl = *(const bf8_t*)&g_w2t_l[gb];
#pragma unroll
          for (int i = 0; i < 4; ++i)
            h2acc[i][j] = __builtin_amdgcn_mfma_f32_16x16x32_bf16(ah[i], bh, h2acc[i][j], 0, 0, 0);
#pragma unroll
          for (int i = 0; i < 4; ++i)
            h2acc[i][j] = __builtin_amdgcn_mfma_f32_16x16x32_bf16(al[i], bh, h2acc[i][j], 0, 0, 0);
#pragma unroll
          for (int i = 0; i < 4; ++i)
            h2acc[i][j] = __builtin_amdgcn_mfma_f32_16x16x32_bf16(ah[i], bl, h2acc[i][j], 0, 0, 0);
        }
      }
    }
  }
  // ---------------- epilogue: write h2 partial (f32) ----------------
  float* outp = g_h2p[zp];
#pragma unroll
  for (int j = 0; j < 4; ++j) {
    int col = wcol * 64 + j * 16 + ln15;
#pragma unroll
    for (int i = 0; i < 4; ++i)
#pragma unroll
      for (int reg = 0; reg < 4; ++reg) {
        int r = row0 + wrow * 64 + i * 16 + q * 4 + reg;
        if (r < kN) outp[(size_t)r * 128 + col] = h2acc[i][j][reg];
      }
  }
}

// ---- fused partial-sum (2) + layer-2 scores; materializes g_h2 ----
__global__ __launch_bounds__(256) void k_scores2(const float* __restrict__ asrc,
                                                 const float* __restrict__ adst) {
  const int lane = threadIdx.x & 63;
  const int n = (blockIdx.x * 256 + threadIdx.x) >> 6;
  if (n >= kN) return;
  const size_t o = (size_t)n * 128;
  float v0 = g_h2p[0][o + lane]      + g_h2p[1][o + lane];
  float v1 = g_h2p[0][o + 64 + lane] + g_h2p[1][o + 64 + lane];
  g_h2[o + lane] = v0;
  g_h2[o + 64 + lane] = v1;
  float s = v0 * asrc[lane] + v1 * asrc[64 + lane];
  float d = v0 * adst[lane] + v1 * adst[64 + lane];
#pragma unroll
  for (int off = 32; off > 0; off >>= 1) {
    s += __shfl_down(s, off);
    d += __shfl_down(d, off);
  }
  if (lane == 0) { g_es2[n] = s; g_ed2[n] = d; }
}

// ---- layer-2 aggregation: 2 edges/iter, float4 gathers + fused FC ----------
__global__ __launch_bounds__(256) void k_agg2x(const float* __restrict__ b2,
    const float* __restrict__ fcw, const float* __restrict__ fcb,
    float* __restrict__ out) {
  const int lane = threadIdx.x & 63;
  const int n = (blockIdx.x * 256 + threadIdx.x) >> 6;
  if (n >= kN) return;
  const int beg = g_ptr[n], end = g_ptr[n + 1];
  const float ed = g_ed2[n];
  const int half = lane >> 5, hl = lane & 31;
  float zp = 0.f;
  float acc[4] = {};
  for (int base = beg; base < end; base += 64) {
    const int cnt = min(64, end - base);
    int s = 0; float w = 0.f;
    if (lane < cnt) {
      s = g_srcs[base + lane];
      w = __expf(lrelu(g_es2[s] + ed));
      zp += w;
    }
    const int pairs = (cnt + 1) >> 1;
    for (int p = 0; p < pairs; ++p) {
      int ei = 2 * p + half;
      int   sj = __shfl(s, ei);
      float wj = __shfl(w, ei);
      float4 f = *(const float4*)(g_h2 + (size_t)sj * 128 + hl * 4);
      acc[0] += wj * f.x; acc[1] += wj * f.y;
      acc[2] += wj * f.z; acc[3] += wj * f.w;
    }
  }
#pragma unroll
  for (int off = 1; off < 64; off <<= 1) zp += __shfl_xor(zp, off);
#pragma unroll
  for (int k = 0; k < 4; ++k) acc[k] += __shfl_xor(acc[k], 32);
  float invz = 1.f / zp;
  float v0 = acc[0] * invz + b2[hl * 4 + 0];
  float v1 = acc[1] * invz + b2[hl * 4 + 1];
  float v2 = acc[2] * invz + b2[hl * 4 + 2];
  float v3 = acc[3] * invz + b2[hl * 4 + 3];
  float s = v0 * fcw[hl * 4 + 0] + v1 * fcw[hl * 4 + 1]
          + v2 * fcw[hl * 4 + 2] + v3 * fcw[hl * 4 + 3];
#pragma unroll
  for (int off = 16; off > 0; off >>= 1) s += __shfl_xor(s, off);
  if (lane == 0) out[n] = s + fcb[0];
}

extern "C" void kernel_launch(void* const* d_in, const int* in_sizes, int n_in,
                              void* d_out, int out_size, void* d_ws, size_t ws_size,
                              hipStream_t stream) {
  const float* x   = (const float*)d_in[0];
  const int*   ei  = (const int*)d_in[1];
  const float* W1  = (const float*)d_in[2];
  const float* a1s = (const float*)d_in[3];
  const float* a1d = (const float*)d_in[4];
  const float* b1  = (const float*)d_in[5];
  const float* W2  = (const float*)d_in[6];
  const float* a2s = (const float*)d_in[7];
  const float* a2d = (const float*)d_in[8];
  const float* b2  = (const float*)d_in[9];
  const float* fcw = (const float*)d_in[10];
  const float* fcb = (const float*)d_in[11];
  float* out = (float*)d_out;
  (void)d_ws; (void)ws_size; (void)in_sizes; (void)n_in; (void)out_size;

  // ---- CSR build (dst-sorted) + weight conversion ----
  k_zero_deg<<<(kN + 255) / 256, 256, 0, stream>>>();
  k_hist<<<(kEt + 255) / 256, 256, 0, stream>>>(ei);
  k_scan<<<1, 256, 0, stream>>>();
  k_scatter<<<(kEt + 255) / 256, 256, 0, stream>>>(ei);
  k_convw<<<512, 256, 0, stream>>>(W1, W2);

  // ---- layer 1 ----
  k_prep1<<<4, 256, 0, stream>>>(W1, a1s, a1d);
  k_scores1x<<<(kN * 64 + 255) / 256, 256, 0, stream>>>(x);
  k_agg1x<<<(kN * 64 + 255) / 256, 256, 0, stream>>>(x);

  // ---- fused expand + layer-2 GEMM (head-pair split) ----
  dim3 gf(1, (kN + 127) / 128, 2);
  k_fused<<<gf, 256, 0, stream>>>(b1);

  // ---- layer 2 tail ----
  k_scores2<<<(kN * 64 + 255) / 256, 256, 0, stream>>>(a2s, a2d);
  k_agg2x<<<(kN * 64 + 255) / 256, 256, 0, stream>>>(b2, fcw, fcb, out);
}

// Round 11
// 621.755 us; speedup vs baseline: 1.1954x; 1.0306x over previous
//
#include <hip/hip_runtime.h>
#include <cstdint>
#include <cstddef>

constexpr int kN   = 50000;          // nodes
constexpr int kE   = 800000;         // edges (without self loops)
constexpr int kEt  = kE + kN;        // edges + self loops
constexpr float kSlope = 0.2f;       // leaky relu slope

typedef __attribute__((ext_vector_type(8))) short bf8_t;   // 8 bf16 = 4 VGPRs
typedef __attribute__((ext_vector_type(4))) float f4_t;

// ---------------- static device workspace (d_ws unused) ---------------------
__device__ __align__(16) unsigned short g_aggx_h[(size_t)kN * 512]; // agg of x, bf16 hi
__device__ __align__(16) unsigned short g_aggx_l[(size_t)kN * 512]; // bf16 lo residual
__device__ __align__(16) unsigned short g_w1t_h[4 * 128 * 128];     // W1^T per head, hi
__device__ __align__(16) unsigned short g_w1t_l[4 * 128 * 128];
__device__ __align__(16) unsigned short g_w2t_h[128 * 512];         // W2^T, hi
__device__ __align__(16) unsigned short g_w2t_l[128 * 512];
__device__ __align__(16) float g_h2  [(size_t)kN * 128];  // layer-2 pre-agg features
__device__ __align__(16) float g_es1[kN * 4];
__device__ __align__(16) float g_ed1[kN * 4];
__device__ float g_es2[kN];
__device__ float g_ed2[kN];
__device__ __align__(16) float g_p1s[4 * 128];  // folded W1_h @ a1_src_h
__device__ __align__(16) float g_p1d[4 * 128];
// CSR by destination:
__device__ int g_deg[kN];
__device__ int g_ptr[kN + 1];
__device__ int g_cur[kN];
__device__ int g_srcs[kEt];

__device__ __forceinline__ float lrelu(float x) { return x > 0.f ? x : kSlope * x; }

// round-to-nearest-even f32 -> bf16
__device__ __forceinline__ unsigned short f2bf(float v, float& hi_f) {
  unsigned u = __float_as_uint(v);
  unsigned r = (u + 0x7FFFu + ((u >> 16) & 1u)) & 0xFFFF0000u;
  hi_f = __uint_as_float(r);
  return (unsigned short)(r >> 16);
}
__device__ __forceinline__ void split_bf(float v, unsigned short& h, unsigned short& l) {
  float hf, lf;
  h = f2bf(v, hf);
  l = f2bf(v - hf, lf);
}

// ------------------------- CSR build ----------------------------------------
__global__ __launch_bounds__(256) void k_zero_deg() {
  int i = blockIdx.x * 256 + threadIdx.x;
  if (i < kN) g_deg[i] = 0;
}

__global__ __launch_bounds__(256) void k_hist(const int* __restrict__ ei) {
  int e = blockIdx.x * 256 + threadIdx.x;
  if (e >= kEt) return;
  int d = (e < kE) ? ei[kE + e] : e - kE;
  atomicAdd(&g_deg[d], 1);
}

// single-block (1024 thr) exclusive scan -> g_ptr, g_cur
__global__ __launch_bounds__(1024) void k_scan() {
  __shared__ int s_sum[1024];
  const int t = threadIdx.x;
  const int chunk = (kN + 1023) / 1024;        // 49
  const int lo = t * chunk, hi = min(lo + chunk, kN);
  int sum = 0;
  for (int i = lo; i < hi; ++i) sum += g_deg[i];
  s_sum[t] = sum;
  __syncthreads();
  for (int off = 1; off < 1024; off <<= 1) {
    int xv = s_sum[t];
    int yv = (t >= off) ? s_sum[t - off] : 0;
    __syncthreads();
    s_sum[t] = xv + yv;
    __syncthreads();
  }
  int run = s_sum[t] - sum;
  for (int i = lo; i < hi; ++i) {
    g_ptr[i] = run;
    g_cur[i] = run;
    run += g_deg[i];
  }
  if (t == 1023) g_ptr[kN] = run;
}

__global__ __launch_bounds__(256) void k_scatter(const int* __restrict__ ei) {
  int e = blockIdx.x * 256 + threadIdx.x;
  if (e >= kEt) return;
  int s, d;
  if (e < kE) { s = ei[e]; d = ei[kE + e]; } else { s = d = e - kE; }
  int slot = atomicAdd(&g_cur[d], 1);
  g_srcs[slot] = s;
}

// ---- weight conversion: W1 -> per-head W1T hi/lo, W2 -> W2T hi/lo ----------
__global__ __launch_bounds__(256) void k_convw(const float* __restrict__ W1,
                                               const float* __restrict__ W2) {
  int gid = blockIdx.x * 256 + threadIdx.x;   // 0..131071
  if (gid < 65536) {
    int h = gid >> 14, rem = gid & 16383;
    int c = rem >> 7, j = rem & 127;
    float v = W1[(size_t)c * 512 + h * 128 + j];
    unsigned short hh, ll;
    split_bf(v, hh, ll);
    size_t o = ((size_t)h * 128 + j) * 128 + c;
    g_w1t_h[o] = hh; g_w1t_l[o] = ll;
  } else {
    int g2 = gid - 65536;
    int k = g2 >> 7, j = g2 & 127;
    float v = W2[(size_t)k * 128 + j];
    unsigned short hh, ll;
    split_bf(v, hh, ll);
    size_t o = (size_t)j * 512 + k;
    g_w2t_h[o] = hh; g_w2t_l[o] = ll;
  }
}

// ---- fold attention vectors through W1 ----
__global__ __launch_bounds__(256) void k_prep1(const float* __restrict__ W1,
    const float* __restrict__ a1s, const float* __restrict__ a1d) {
  int gid = blockIdx.x * 256 + threadIdx.x;
  if (gid >= 1024) return;
  int which = gid >> 9, idx = gid & 511;
  int h = idx >> 7, k = idx & 127;
  const float* a = which ? a1d : a1s;
  const float* wrow = W1 + (size_t)k * 512 + h * 128;
  float s = 0.f;
#pragma unroll 8
  for (int c = 0; c < 128; ++c) s += wrow[c] * a[h * 128 + c];
  (which ? g_p1d : g_p1s)[idx] = s;
}

// ---- layer-1 scores directly from x ----
__global__ __launch_bounds__(256) void k_scores1x(const float* __restrict__ x) {
  const int lane = threadIdx.x & 63;
  const int n = (blockIdx.x * 256 + threadIdx.x) >> 6;
  if (n >= kN) return;
  float x0 = x[(size_t)n * 128 + lane];
  float x1 = x[(size_t)n * 128 + 64 + lane];
  float s[4], d[4];
#pragma unroll
  for (int h = 0; h < 4; ++h) {
    s[h] = x0 * g_p1s[h * 128 + lane] + x1 * g_p1s[h * 128 + 64 + lane];
    d[h] = x0 * g_p1d[h * 128 + lane] + x1 * g_p1d[h * 128 + 64 + lane];
  }
#pragma unroll
  for (int off = 32; off > 0; off >>= 1) {
#pragma unroll
    for (int h = 0; h < 4; ++h) {
      s[h] += __shfl_down(s[h], off);
      d[h] += __shfl_down(d[h], off);
    }
  }
  if (lane == 0) {
    *(float4*)(g_es1 + (size_t)n * 4) = make_float4(s[0], s[1], s[2], s[3]);
    *(float4*)(g_ed1 + (size_t)n * 4) = make_float4(d[0], d[1], d[2], d[3]);
  }
}

// ---- layer-1 aggregation: 4 edges/iter (16-lane quarters), 2xfloat4/lane ---
__global__ __launch_bounds__(256) void k_agg1x(const float* __restrict__ x) {
  const int lane = threadIdx.x & 63;
  const int n = (blockIdx.x * 256 + threadIdx.x) >> 6;
  if (n >= kN) return;
  const int beg = g_ptr[n], end = g_ptr[n + 1];
  const float4 ed = *(const float4*)(g_ed1 + (size_t)n * 4);
  const int qt = lane >> 4, ql = lane & 15;
  float z0 = 0.f, z1 = 0.f, z2 = 0.f, z3 = 0.f;
  float acc[4][8] = {};
  for (int base = beg; base < end; base += 64) {
    const int cnt = min(64, end - base);
    int s = 0;
    float w0 = 0.f, w1 = 0.f, w2 = 0.f, w3 = 0.f;
    if (lane < cnt) {
      s = g_srcs[base + lane];
      float4 es = *(const float4*)(g_es1 + (size_t)s * 4);
      w0 = __expf(lrelu(es.x + ed.x));
      w1 = __expf(lrelu(es.y + ed.y));
      w2 = __expf(lrelu(es.z + ed.z));
      w3 = __expf(lrelu(es.w + ed.w));
      z0 += w0; z1 += w1; z2 += w2; z3 += w3;
    }
    const int quads = (cnt + 3) >> 2;
    for (int p = 0; p < quads; ++p) {
      int ei = 4 * p + qt;                  // ei >= cnt -> broadcast w = 0
      int   sj = __shfl(s, ei);
      float b0 = __shfl(w0, ei), b1 = __shfl(w1, ei);
      float b2 = __shfl(w2, ei), b3 = __shfl(w3, ei);
      const float* xp = x + (size_t)sj * 128 + ql * 8;
      float4 f0 = *(const float4*)xp;
      float4 f1 = *(const float4*)(xp + 4);
      float fv[8] = {f0.x, f0.y, f0.z, f0.w, f1.x, f1.y, f1.z, f1.w};
#pragma unroll
      for (int k = 0; k < 8; ++k) {
        acc[0][k] += b0 * fv[k];
        acc[1][k] += b1 * fv[k];
        acc[2][k] += b2 * fv[k];
        acc[3][k] += b3 * fv[k];
      }
    }
  }
  // cross-quarter feature reduce
#pragma unroll
  for (int h = 0; h < 4; ++h)
#pragma unroll
    for (int k = 0; k < 8; ++k) {
      acc[h][k] += __shfl_xor(acc[h][k], 16);
      acc[h][k] += __shfl_xor(acc[h][k], 32);
    }
  // z full reduce
#pragma unroll
  for (int off = 1; off < 64; off <<= 1) {
    z0 += __shfl_xor(z0, off); z1 += __shfl_xor(z1, off);
    z2 += __shfl_xor(z2, off); z3 += __shfl_xor(z3, off);
  }
  // quarter qt handles head qt
  float zh = qt == 0 ? z0 : qt == 1 ? z1 : qt == 2 ? z2 : z3;
  float iz = 1.f / zh;
  float v[8];
#pragma unroll
  for (int k = 0; k < 8; ++k)
    v[k] = (qt == 0 ? acc[0][k] : qt == 1 ? acc[1][k] : qt == 2 ? acc[2][k] : acc[3][k]) * iz;
  ushort4 h0, l0, h1, l1;
  split_bf(v[0], h0.x, l0.x); split_bf(v[1], h0.y, l0.y);
  split_bf(v[2], h0.z, l0.z); split_bf(v[3], h0.w, l0.w);
  split_bf(v[4], h1.x, l1.x); split_bf(v[5], h1.y, l1.y);
  split_bf(v[6], h1.z, l1.z); split_bf(v[7], h1.w, l1.w);
  size_t o = (size_t)n * 512 + qt * 128 + ql * 8;
  *(ushort4*)(g_aggx_h + o) = h0; *(ushort4*)(g_aggx_h + o + 4) = h1;
  *(ushort4*)(g_aggx_l + o) = l0; *(ushort4*)(g_aggx_l + o + 4) = l1;
}

// ------- fused layer-1 expand + layer-2 GEMM, 64-row tiles ------------------
// 256 thr / 4 waves (2 row-waves x 2 col-waves); each wave 2x4 16-tiles.
// grid.y = 782 ~= 3 blocks/CU at ~3 waves/SIMD. h1 round-trips through LDS.
__global__ __launch_bounds__(256) void k_fused(const float* __restrict__ b1) {
  __shared__ unsigned short smem[9216];     // 18432 B
  unsigned short* S1h = smem;               // A staging [64][40]
  unsigned short* S1l = smem + 2560;
  unsigned short* Hh  = smem;               // h1 chunk [64][72]
  unsigned short* Hl  = smem + 4608;        // (overlaps S1 — barrier-separated)
  const int t = threadIdx.x;
  const int lane = t & 63, w = t >> 6;
  const int wrow = w >> 1, wcol = w & 1;
  const int ln15 = lane & 15, q = lane >> 4, qo = q * 8;
  const int row0 = blockIdx.y * 64;

  f4_t h2acc[2][4] = {};
#pragma unroll 1
  for (int h = 0; h < 4; ++h) {
    // ---------------- phase 1: h1acc = aggx_h @ W1_h ----------------
    f4_t h1acc[2][4] = {};
#pragma unroll 1
    for (int ks = 0; ks < 128; ks += 32) {
      __syncthreads();   // protect S1 (overlaps H) from previous readers
      {
        int r = t >> 2, kq = (t & 3) << 3;
        uint4 vh = make_uint4(0u, 0u, 0u, 0u), vl = vh;
        if (row0 + r < kN) {
          size_t ga = (size_t)(row0 + r) * 512 + h * 128 + ks + kq;
          vh = *(const uint4*)&g_aggx_h[ga];
          vl = *(const uint4*)&g_aggx_l[ga];
        }
        *(uint4*)&S1h[r * 40 + kq] = vh;
        *(uint4*)&S1l[r * 40 + kq] = vl;
      }
      __syncthreads();
      bf8_t ah[2], al[2];
#pragma unroll
      for (int i = 0; i < 2; ++i) {
        int ma = (wrow * 32 + i * 16 + ln15) * 40 + qo;
        ah[i] = *(const bf8_t*)&S1h[ma];
        al[i] = *(const bf8_t*)&S1l[ma];
      }
#pragma unroll
      for (int j = 0; j < 4; ++j) {
        size_t gb = ((size_t)h * 128 + wcol * 64 + j * 16 + ln15) * 128 + ks + qo;
        bf8_t bh = *(const bf8_t*)&g_w1t_h[gb];
        bf8_t bl = *(const bf8_t*)&g_w1t_l[gb];
#pragma unroll
        for (int i = 0; i < 2; ++i)
          h1acc[i][j] = __builtin_amdgcn_mfma_f32_16x16x32_bf16(ah[i], bh, h1acc[i][j], 0, 0, 0);
#pragma unroll
        for (int i = 0; i < 2; ++i)
          h1acc[i][j] = __builtin_amdgcn_mfma_f32_16x16x32_bf16(al[i], bh, h1acc[i][j], 0, 0, 0);
#pragma unroll
        for (int i = 0; i < 2; ++i)
          h1acc[i][j] = __builtin_amdgcn_mfma_f32_16x16x32_bf16(ah[i], bl, h1acc[i][j], 0, 0, 0);
      }
    }
    // ---------------- phase 2: bias + relu + split-bf16 ----------------
    unsigned pk[2][4][4];
#pragma unroll
    for (int j = 0; j < 4; ++j) {
      float bv = b1[h * 128 + wcol * 64 + j * 16 + ln15];
#pragma unroll
      for (int i = 0; i < 2; ++i)
#pragma unroll
        for (int reg = 0; reg < 4; ++reg) {
          float v = fmaxf(h1acc[i][j][reg] + bv, 0.f);
          unsigned short hb, lb;
          split_bf(v, hb, lb);
          pk[i][j][reg] = ((unsigned)hb << 16) | lb;
        }
    }
    // ---------------- phase 3: h2 += h1_h @ W2_h (two 64-col chunks) --------
#pragma unroll 1
    for (int cc = 0; cc < 2; ++cc) {
      __syncthreads();   // protect H overwrite from previous readers
      if (wcol == cc) {
#pragma unroll
        for (int i = 0; i < 2; ++i)
#pragma unroll
          for (int j = 0; j < 4; ++j)
#pragma unroll
            for (int reg = 0; reg < 4; ++reg) {
              int rl = wrow * 32 + i * 16 + q * 4 + reg;
              int cl = j * 16 + ln15;
              Hh[rl * 72 + cl] = (unsigned short)(pk[i][j][reg] >> 16);
              Hl[rl * 72 + cl] = (unsigned short)(pk[i][j][reg] & 0xFFFFu);
            }
      }
      __syncthreads();
#pragma unroll 1
      for (int kc = 0; kc < 64; kc += 32) {
        bf8_t ah[2], al[2];
#pragma unroll
        for (int i = 0; i < 2; ++i) {
          int ma = (wrow * 32 + i * 16 + ln15) * 72 + kc + qo;
          ah[i] = *(const bf8_t*)&Hh[ma];
          al[i] = *(const bf8_t*)&Hl[ma];
        }
#pragma unroll
        for (int j = 0; j < 4; ++j) {
          size_t gb = (size_t)(wcol * 64 + j * 16 + ln15) * 512 + h * 128 + cc * 64 + kc + qo;
          bf8_t bh = *(const bf8_t*)&g_w2t_h[gb];
          bf8_t bl = *(const bf8_t*)&g_w2t_l[gb];
#pragma unroll
          for (int i = 0; i < 2; ++i)
            h2acc[i][j] = __builtin_amdgcn_mfma_f32_16x16x32_bf16(ah[i], bh, h2acc[i][j], 0, 0, 0);
#pragma unroll
          for (int i = 0; i < 2; ++i)
            h2acc[i][j] = __builtin_amdgcn_mfma_f32_16x16x32_bf16(al[i], bh, h2acc[i][j], 0, 0, 0);
#pragma unroll
          for (int i = 0; i < 2; ++i)
            h2acc[i][j] = __builtin_amdgcn_mfma_f32_16x16x32_bf16(ah[i], bl, h2acc[i][j], 0, 0, 0);
        }
      }
    }
  }
  // ---------------- epilogue: write h2 (f32) ----------------
#pragma unroll
  for (int j = 0; j < 4; ++j) {
    int col = wcol * 64 + j * 16 + ln15;
#pragma unroll
    for (int i = 0; i < 2; ++i)
#pragma unroll
      for (int reg = 0; reg < 4; ++reg) {
        int r = row0 + wrow * 32 + i * 16 + q * 4 + reg;
        if (r < kN) g_h2[(size_t)r * 128 + col] = h2acc[i][j][reg];
      }
  }
}

// ---- layer-2 scores (reads h2 directly) ----
__global__ __launch_bounds__(256) void k_scores2(const float* __restrict__ asrc,
                                                 const float* __restrict__ adst) {
  const int lane = threadIdx.x & 63;
  const int n = (blockIdx.x * 256 + threadIdx.x) >> 6;
  if (n >= kN) return;
  const size_t o = (size_t)n * 128;
  float v0 = g_h2[o + lane];
  float v1 = g_h2[o + 64 + lane];
  float s = v0 * asrc[lane] + v1 * asrc[64 + lane];
  float d = v0 * adst[lane] + v1 * adst[64 + lane];
#pragma unroll
  for (int off = 32; off > 0; off >>= 1) {
    s += __shfl_down(s, off);
    d += __shfl_down(d, off);
  }
  if (lane == 0) { g_es2[n] = s; g_ed2[n] = d; }
}

// ---- layer-2 aggregation: 4 edges/iter (quarters) + fused FC ---------------
__global__ __launch_bounds__(256) void k_agg2x(const float* __restrict__ b2,
    const float* __restrict__ fcw, const float* __restrict__ fcb,
    float* __restrict__ out) {
  const int lane = threadIdx.x & 63;
  const int n = (blockIdx.x * 256 + threadIdx.x) >> 6;
  if (n >= kN) return;
  const int beg = g_ptr[n], end = g_ptr[n + 1];
  const float ed = g_ed2[n];
  const int qt = lane >> 4, ql = lane & 15;
  float zp = 0.f;
  float acc[8] = {};
  for (int base = beg; base < end; base += 64) {
    const int cnt = min(64, end - base);
    int s = 0; float w = 0.f;
    if (lane < cnt) {
      s = g_srcs[base + lane];
      w = __expf(lrelu(g_es2[s] + ed));
      zp += w;
    }
    const int quads = (cnt + 3) >> 2;
    for (int p = 0; p < quads; ++p) {
      int ei = 4 * p + qt;
      int   sj = __shfl(s, ei);
      float wj = __shfl(w, ei);
      const float* hp = g_h2 + (size_t)sj * 128 + ql * 8;
      float4 f0 = *(const float4*)hp;
      float4 f1 = *(const float4*)(hp + 4);
      acc[0] += wj * f0.x; acc[1] += wj * f0.y;
      acc[2] += wj * f0.z; acc[3] += wj * f0.w;
      acc[4] += wj * f1.x; acc[5] += wj * f1.y;
      acc[6] += wj * f1.z; acc[7] += wj * f1.w;
    }
  }
#pragma unroll
  for (int off = 1; off < 64; off <<= 1) zp += __shfl_xor(zp, off);
#pragma unroll
  for (int k = 0; k < 8; ++k) {
    acc[k] += __shfl_xor(acc[k], 16);
    acc[k] += __shfl_xor(acc[k], 32);
  }
  float invz = 1.f / zp;
  float s = 0.f;
#pragma unroll
  for (int k = 0; k < 8; ++k)
    s += (acc[k] * invz + b2[ql * 8 + k]) * fcw[ql * 8 + k];
#pragma unroll
  for (int off = 8; off > 0; off >>= 1) s += __shfl_xor(s, off);
  if (lane == 0) out[n] = s + fcb[0];
}

extern "C" void kernel_launch(void* const* d_in, const int* in_sizes, int n_in,
                              void* d_out, int out_size, void* d_ws, size_t ws_size,
                              hipStream_t stream) {
  const float* x   = (const float*)d_in[0];
  const int*   ei  = (const int*)d_in[1];
  const float* W1  = (const float*)d_in[2];
  const float* a1s = (const float*)d_in[3];
  const float* a1d = (const float*)d_in[4];
  const float* b1  = (const float*)d_in[5];
  const float* W2  = (const float*)d_in[6];
  const float* a2s = (const float*)d_in[7];
  const float* a2d = (const float*)d_in[8];
  const float* b2  = (const float*)d_in[9];
  const float* fcw = (const float*)d_in[10];
  const float* fcb = (const float*)d_in[11];
  float* out = (float*)d_out;
  (void)d_ws; (void)ws_size; (void)in_sizes; (void)n_in; (void)out_size;

  // ---- CSR build (dst-sorted) + weight conversion ----
  k_zero_deg<<<(kN + 255) / 256, 256, 0, stream>>>();
  k_hist<<<(kEt + 255) / 256, 256, 0, stream>>>(ei);
  k_scan<<<1, 1024, 0, stream>>>();
  k_scatter<<<(kEt + 255) / 256, 256, 0, stream>>>(ei);
  k_convw<<<512, 256, 0, stream>>>(W1, W2);

  // ---- layer 1 ----
  k_prep1<<<4, 256, 0, stream>>>(W1, a1s, a1d);
  k_scores1x<<<(kN * 64 + 255) / 256, 256, 0, stream>>>(x);
  k_agg1x<<<(kN * 64 + 255) / 256, 256, 0, stream>>>(x);

  // ---- fused expand + layer-2 GEMM (64-row tiles) ----
  dim3 gf(1, (kN + 63) / 64, 1);
  k_fused<<<gf, 256, 0, stream>>>(b1);

  // ---- layer 2 tail ----
  k_scores2<<<(kN * 64 + 255) / 256, 256, 0, stream>>>(a2s, a2d);
  k_agg2x<<<(kN * 64 + 255) / 256, 256, 0, stream>>>(b2, fcw, fcb, out);
}